// Round 10
// baseline (1110.995 us; speedup 1.0000x reference)
//
#include <hip/hip_runtime.h>
#include <math.h>

#define N_NODES 204800
#define N_EDGES 600000
#define N_GRAPH 3200
#define H 128
#define NF 16
#define EF 5
#define GF 8
#define LAYERS 6
#define SEG 64
#define EPSV 1e-5f
#define NB_SCAN 800   // N_NODES / 256
#define NBLK 3200     // N_NODES / 64 (gemm blocks)

typedef __attribute__((ext_vector_type(8))) short bf16x8;
typedef __attribute__((ext_vector_type(4))) float f32x4;

__device__ inline float bf2f(unsigned int u) {            // low 16 bits = bf16
    return __builtin_bit_cast(float, u << 16);
}
__device__ inline unsigned short f2bf(float f) {          // RNE
    unsigned int u = __builtin_bit_cast(unsigned int, f);
    u += 0x7fffu + ((u >> 16) & 1u);
    return (unsigned short)(u >> 16);
}
__device__ inline float uif(unsigned int u) { return __builtin_bit_cast(float, u); }

// ---------------- K1: hb = bf16(x @ node_w + node_b) ----------------
// 16 threads/node, 8 outputs/thread, vectorized x loads (was: 32 thr/node, scalar x).
__global__ __launch_bounds__(256) void k_init_h(
    const float* __restrict__ x, const float* __restrict__ node_w,
    const float* __restrict__ node_b, unsigned short* __restrict__ hb)
{
    int idx = blockIdx.x * 256 + threadIdx.x;   // n*16 + c8
    int n = idx >> 4, c0 = (idx & 15) * 8;
    const float4* xr = (const float4*)(x + (size_t)n * NF);
    float4 x0 = xr[0], x1 = xr[1], x2 = xr[2], x3 = xr[3];
    float xa[16] = {x0.x, x0.y, x0.z, x0.w, x1.x, x1.y, x1.z, x1.w,
                    x2.x, x2.y, x2.z, x2.w, x3.x, x3.y, x3.z, x3.w};
    float4 a0 = *(const float4*)(node_b + c0);
    float4 a1 = *(const float4*)(node_b + c0 + 4);
#pragma unroll
    for (int k = 0; k < NF; ++k) {
        float xv = xa[k];
        float4 w0 = *(const float4*)(node_w + k * H + c0);
        float4 w1 = *(const float4*)(node_w + k * H + c0 + 4);
        a0.x += xv * w0.x; a0.y += xv * w0.y; a0.z += xv * w0.z; a0.w += xv * w0.w;
        a1.x += xv * w1.x; a1.y += xv * w1.y; a1.z += xv * w1.z; a1.w += xv * w1.w;
    }
    uint4 pk;
    pk.x = (unsigned int)f2bf(a0.x) | ((unsigned int)f2bf(a0.y) << 16);
    pk.y = (unsigned int)f2bf(a0.z) | ((unsigned int)f2bf(a0.w) << 16);
    pk.z = (unsigned int)f2bf(a1.x) | ((unsigned int)f2bf(a1.y) << 16);
    pk.w = (unsigned int)f2bf(a1.z) | ((unsigned int)f2bf(a1.w) << 16);
    *(uint4*)(hb + (size_t)n * H + c0) = pk;
}

// ---------------- W repack: [rel|root] -> MFMA B-fragment order, bf16 ----------------
// wp[i][nb(8)][ks(8)][lane(64)][8]  ; ks 0..3 = rel (agg half), 4..7 = root (h half)
__global__ __launch_bounds__(64) void k_wpack(
    const float* __restrict__ relw, const float* __restrict__ rootw,
    unsigned short* __restrict__ wp)
{
    int bid = blockIdx.x;          // i*64 + nb*8 + ks
    int i = bid >> 6, f = bid & 63;
    int nb = f >> 3, ks = f & 7;
    int l = threadIdx.x;
    const float* src = (ks < 4) ? (relw + (size_t)i * H * H) : (rootw + (size_t)i * H * H);
    int ksl = ks & 3;
    int col = nb * 16 + (l & 15);
    int kbase = ksl * 32 + (l >> 4) * 8;
    unsigned short tmp[8];
#pragma unroll
    for (int m = 0; m < 8; ++m)
        tmp[m] = f2bf(src[(size_t)(kbase + m) * H + col]);
    *(uint4*)(wp + ((size_t)bid * 64 + l) * 8) = *(uint4*)tmp;
}

// gate_w1 pack: gwp[nb(8)][ks(4)][lane(64)][8]
__global__ __launch_bounds__(64) void k_wpack_gate(
    const float* __restrict__ gw1, unsigned short* __restrict__ gwp)
{
    int bid = blockIdx.x;          // nb*4 + ks
    int nb = bid >> 2, ks = bid & 3;
    int l = threadIdx.x;
    int col = nb * 16 + (l & 15);
    int kbase = ks * 32 + (l >> 4) * 8;
    unsigned short tmp[8];
#pragma unroll
    for (int m = 0; m < 8; ++m)
        tmp[m] = f2bf(gw1[(size_t)(kbase + m) * H + col]);
    *(uint4*)(gwp + ((size_t)bid * 64 + l) * 8) = *(uint4*)tmp;
}

// ---------------- CSR build: deg -> scan -> scatter ----------------
__global__ __launch_bounds__(256) void k_deg(const int* __restrict__ ei, int* __restrict__ deg)
{
    int e = blockIdx.x * 256 + threadIdx.x;
    if (e < N_EDGES) atomicAdd(&deg[ei[N_EDGES + e]], 1);
}

__global__ __launch_bounds__(256) void k_scan1(
    const int* __restrict__ deg, int* __restrict__ rowtmp, int* __restrict__ bsum)
{
    __shared__ int sh[256];
    int t = threadIdx.x;
    int i = blockIdx.x * 256 + t;
    int v = deg[i];
    sh[t] = v;
    __syncthreads();
    for (int off = 1; off < 256; off <<= 1) {
        int a = (t >= off) ? sh[t - off] : 0;
        __syncthreads();
        sh[t] += a;
        __syncthreads();
    }
    rowtmp[i] = sh[t] - v;                 // exclusive
    if (t == 255) bsum[blockIdx.x] = sh[255];
}

__global__ void k_scan2(int* __restrict__ bsum, int* __restrict__ boff)  // 1 block x 256
{
    __shared__ int sh[256];
    __shared__ int carry;
    int t = threadIdx.x;
    if (t == 0) carry = 0;
    __syncthreads();
    for (int base = 0; base < NB_SCAN; base += 256) {
        int i = base + t;
        int v = (i < NB_SCAN) ? bsum[i] : 0;
        sh[t] = v;
        __syncthreads();
        for (int off = 1; off < 256; off <<= 1) {
            int a = (t >= off) ? sh[t - off] : 0;
            __syncthreads();
            sh[t] += a;
            __syncthreads();
        }
        if (i < NB_SCAN) boff[i] = carry + sh[t] - v;
        __syncthreads();
        if (t == 0) carry += sh[255];
        __syncthreads();
    }
}

__global__ __launch_bounds__(256) void k_scan3(
    const int* __restrict__ rowtmp, const int* __restrict__ boff,
    int* __restrict__ rowptr, int* __restrict__ cursor)
{
    int i = blockIdx.x * 256 + threadIdx.x;
    int r = rowtmp[i] + boff[blockIdx.x];
    rowptr[i] = r;
    cursor[i] = r;
    if (i == 0) rowptr[N_NODES] = N_EDGES;
}

// scatter 32B records: {src, ea0..ea4, pad, pad}
__global__ __launch_bounds__(256) void k_scatter(
    const int* __restrict__ ei, const float* __restrict__ eattr,
    int* __restrict__ cursor, uint4* __restrict__ recs)
{
    int e = blockIdx.x * 256 + threadIdx.x;
    if (e >= N_EDGES) return;
    int d = ei[N_EDGES + e];
    const float* ar = eattr + (size_t)e * EF;
    float c0 = ar[0], c1 = ar[1], c2 = ar[2], c3 = ar[3], c4 = ar[4];
    int pos = atomicAdd(&cursor[d], 1);
    uint4 q0, q1;
    q0.x = (unsigned int)ei[e];
    q0.y = __builtin_bit_cast(unsigned int, c0);
    q0.z = __builtin_bit_cast(unsigned int, c1);
    q0.w = __builtin_bit_cast(unsigned int, c2);
    q1.x = __builtin_bit_cast(unsigned int, c3);
    q1.y = __builtin_bit_cast(unsigned int, c4);
    q1.z = 0; q1.w = 0;
    recs[2 * (size_t)pos]     = q0;
    recs[2 * (size_t)pos + 1] = q1;
}

// ---------------- K3: pull aggregation; 4 nodes/wave, branch-free pipelined --------
// Per iteration: 4 gathers in flight + next-iteration rec prefetch (hides rec->gather
// 2-hop chain). Invalid slots load recs[0] (in-bounds, finite) with weight cndmask'd to 0.
#define EDGE_C(q0, q1, hv, vmask, A0, A1)                                      \
    {                                                                          \
        float ea0 = eb2.x, ea1 = eb2.y;                                        \
        float c0 = uif((q0).y), c1 = uif((q0).z), c2 = uif((q0).w);            \
        float c3 = uif((q1).x), c4 = uif((q1).y);                              \
        ea0 += c0 * ew2[0].x + c1 * ew2[1].x + c2 * ew2[2].x + c3 * ew2[3].x + c4 * ew2[4].x; \
        ea1 += c0 * ew2[0].y + c1 * ew2[1].y + c2 * ew2[2].y + c3 * ew2[3].y + c4 * ew2[4].y; \
        ea0 = (vmask) ? ea0 : 0.f;                                             \
        ea1 = (vmask) ? ea1 : 0.f;                                             \
        A0 += bf2f((hv) & 0xffffu) * ea0;                                      \
        A1 += bf2f((hv) >> 16) * ea1;                                          \
    }

__global__ __launch_bounds__(256) void k_agg(
    const int* __restrict__ rowptr, const uint4* __restrict__ recs,
    const float* __restrict__ edge_w, const float* __restrict__ edge_b,
    const unsigned short* __restrict__ hb, unsigned short* __restrict__ aggb)
{
    int w = threadIdx.x >> 6, l = threadIdx.x & 63;
    int n = blockIdx.x * 16 + w * 4;           // this wave: nodes n..n+3; grid = N/16
    float2 ew2[EF];
#pragma unroll
    for (int k = 0; k < EF; ++k) ew2[k] = ((const float2*)(edge_w + k * H))[l];
    float2 eb2 = ((const float2*)edge_b)[l];

    int j0 = rowptr[n],     e0 = rowptr[n + 1];
    int j1 = e0,            e1 = rowptr[n + 2];
    int j2 = e1,            e2 = rowptr[n + 3];
    int j3 = e2,            e3 = rowptr[n + 4];
    int iters = max(max(e0 - j0, e1 - j1), max(e2 - j2, e3 - j3));

    float a00 = 0.f, a01 = 0.f, a10 = 0.f, a11 = 0.f;
    float a20 = 0.f, a21 = 0.f, a30 = 0.f, a31 = 0.f;

    // prime first recs
    int i0 = (j0 < e0) ? j0 : 0;
    int i1 = (j1 < e1) ? j1 : 0;
    int i2 = (j2 < e2) ? j2 : 0;
    int i3 = (j3 < e3) ? j3 : 0;
    uint4 qa0 = recs[2 * i0], qa1 = recs[2 * i0 + 1];
    uint4 qb0 = recs[2 * i1], qb1 = recs[2 * i1 + 1];
    uint4 qc0 = recs[2 * i2], qc1 = recs[2 * i2 + 1];
    uint4 qd0 = recs[2 * i3], qd1 = recs[2 * i3 + 1];

    for (int it = 0; it < iters; ++it) {
        // issue the 4 gathers for the current recs
        unsigned int hva = *(const unsigned int*)(hb + (size_t)(int)qa0.x * H + 2 * l);
        unsigned int hvb = *(const unsigned int*)(hb + (size_t)(int)qb0.x * H + 2 * l);
        unsigned int hvc = *(const unsigned int*)(hb + (size_t)(int)qc0.x * H + 2 * l);
        unsigned int hvd = *(const unsigned int*)(hb + (size_t)(int)qd0.x * H + 2 * l);
        bool v0 = j0 < e0, v1 = j1 < e1, v2 = j2 < e2, v3 = j3 < e3;
        ++j0; ++j1; ++j2; ++j3;
        // prefetch next recs (overlaps the in-flight gathers)
        i0 = (j0 < e0) ? j0 : 0;
        i1 = (j1 < e1) ? j1 : 0;
        i2 = (j2 < e2) ? j2 : 0;
        i3 = (j3 < e3) ? j3 : 0;
        uint4 na0 = recs[2 * i0], na1 = recs[2 * i0 + 1];
        uint4 nb0 = recs[2 * i1], nb1 = recs[2 * i1 + 1];
        uint4 nc0 = recs[2 * i2], nc1 = recs[2 * i2 + 1];
        uint4 nd0 = recs[2 * i3], nd1 = recs[2 * i3 + 1];
        // compute with current recs + gathered rows
        EDGE_C(qa0, qa1, hva, v0, a00, a01);
        EDGE_C(qb0, qb1, hvb, v1, a10, a11);
        EDGE_C(qc0, qc1, hvc, v2, a20, a21);
        EDGE_C(qd0, qd1, hvd, v3, a30, a31);
        qa0 = na0; qa1 = na1; qb0 = nb0; qb1 = nb1;
        qc0 = nc0; qc1 = nc1; qd0 = nd0; qd1 = nd1;
    }

    *(unsigned int*)(aggb + (size_t)n * H + 2 * l) =
        (unsigned int)f2bf(a00) | ((unsigned int)f2bf(a01) << 16);
    *(unsigned int*)(aggb + (size_t)(n + 1) * H + 2 * l) =
        (unsigned int)f2bf(a10) | ((unsigned int)f2bf(a11) << 16);
    *(unsigned int*)(aggb + (size_t)(n + 2) * H + 2 * l) =
        (unsigned int)f2bf(a20) | ((unsigned int)f2bf(a21) << 16);
    *(unsigned int*)(aggb + (size_t)(n + 3) * H + 2 * l) =
        (unsigned int)f2bf(a30) | ((unsigned int)f2bf(a31) << 16);
}

// ---------------- K4: MFMA dual-GEMM, A in swizzled LDS; BN partials -> pbuf (no atomics)
// block = 256 (4 waves); tile 64 rows x 128 cols; wave w: cols [w*32, w*32+32)
__global__ __launch_bounds__(256) void k_gemm_mfma(
    const unsigned short* __restrict__ aggb,
    const unsigned short* __restrict__ hb,
    const unsigned short* __restrict__ wp,      // this layer's 64KB packed [rel|root]
    const float* __restrict__ relb,
    unsigned short* __restrict__ h2b,
    float* __restrict__ pbuf)                   // [256][NBLK] per-block partials
{
    __shared__ unsigned short smA[64 * 128];    // 16KB agg tile (swizzled)
    __shared__ unsigned short smH[64 * 128];    // 16KB h tile (swizzled)
    int tid = threadIdx.x;
    int w = tid >> 6, l = tid & 63;
    int bid = blockIdx.x;
    int n0 = bid * 64;
    int lr = l & 15, hi = l >> 4;

    // ---- stage both A tiles: coalesced global read, swizzled LDS write ----
    const char* aggp = (const char*)(aggb + (size_t)n0 * H);
    const char* hbp  = (const char*)(hb  + (size_t)n0 * H);
    char* sA = (char*)smA;
    char* sH = (char*)smH;
#pragma unroll
    for (int i = 0; i < 4; ++i) {
        int o = (i * 256 + tid) * 16;           // linear byte offset in 16KB tile
        int row = o >> 8;                       // /256B per row
        int col = o & 255;
        int scol = col ^ ((row & 7) << 4);
        uint4 va = *(const uint4*)(aggp + o);
        uint4 vh = *(const uint4*)(hbp + o);
        *(uint4*)(sA + row * 256 + scol) = va;
        *(uint4*)(sH + row * 256 + scol) = vh;
    }
    __syncthreads();

    f32x4 acc[4][2];
#pragma unroll
    for (int rb = 0; rb < 4; ++rb) {
        acc[rb][0] = (f32x4){0.f, 0.f, 0.f, 0.f};
        acc[rb][1] = (f32x4){0.f, 0.f, 0.f, 0.f};
    }

    const bf16x8* wv = (const bf16x8*)wp;
#pragma unroll
    for (int ks = 0; ks < 4; ++ks) {            // agg half: A from LDS
        bf16x8 b0 = wv[((2 * w + 0) * 8 + ks) * 64 + l];
        bf16x8 b1 = wv[((2 * w + 1) * 8 + ks) * 64 + l];
#pragma unroll
        for (int rb = 0; rb < 4; ++rb) {
            int r = rb * 16 + lr;
            int bc = (ks * 64 + hi * 16) ^ ((r & 7) << 4);
            bf16x8 a = *(const bf16x8*)(sA + r * 256 + bc);
            acc[rb][0] = __builtin_amdgcn_mfma_f32_16x16x32_bf16(a, b0, acc[rb][0], 0, 0, 0);
            acc[rb][1] = __builtin_amdgcn_mfma_f32_16x16x32_bf16(a, b1, acc[rb][1], 0, 0, 0);
        }
    }
#pragma unroll
    for (int ks = 0; ks < 4; ++ks) {            // root half: A from LDS
        bf16x8 b0 = wv[((2 * w + 0) * 8 + 4 + ks) * 64 + l];
        bf16x8 b1 = wv[((2 * w + 1) * 8 + 4 + ks) * 64 + l];
#pragma unroll
        for (int rb = 0; rb < 4; ++rb) {
            int r = rb * 16 + lr;
            int bc = (ks * 64 + hi * 16) ^ ((r & 7) << 4);
            bf16x8 a = *(const bf16x8*)(sH + r * 256 + bc);
            acc[rb][0] = __builtin_amdgcn_mfma_f32_16x16x32_bf16(a, b0, acc[rb][0], 0, 0, 0);
            acc[rb][1] = __builtin_amdgcn_mfma_f32_16x16x32_bf16(a, b1, acc[rb][1], 0, 0, 0);
        }
    }

    // epilogue: bias, bf16 store, per-block BN partials (plain stores, no atomics)
#pragma unroll
    for (int nbl = 0; nbl < 2; ++nbl) {
        int col = w * 32 + nbl * 16 + lr;
        float bs = relb[col];
        float csum = 0.f, csq = 0.f;
#pragma unroll
        for (int rb = 0; rb < 4; ++rb) {
#pragma unroll
            for (int jj = 0; jj < 4; ++jj) {
                float v = acc[rb][nbl][jj] + bs;
                h2b[(size_t)(n0 + rb * 16 + hi * 4 + jj) * H + col] = f2bf(v);
                csum += v; csq += v * v;
            }
        }
        csum += __shfl_xor(csum, 16); csum += __shfl_xor(csum, 32);
        csq  += __shfl_xor(csq, 16);  csq  += __shfl_xor(csq, 32);
        if (hi == 0) {
            pbuf[(size_t)col * NBLK + bid]         = csum;
            pbuf[(size_t)(128 + col) * NBLK + bid] = csq;
        }
    }
}

// ---------------- K5: reduce pbuf -> scale/shift (one block per column) ----------------
__global__ __launch_bounds__(256) void k_red(
    const float* __restrict__ pbuf, const float* __restrict__ gamma,
    const float* __restrict__ beta, float* __restrict__ stats)
{
    __shared__ float sh[8];
    int c = blockIdx.x;                 // 0..127
    int t = threadIdx.x;
    float s = 0.f, q = 0.f;
    const float* ps = pbuf + (size_t)c * NBLK;
    const float* pq = pbuf + (size_t)(128 + c) * NBLK;
    for (int i = t; i < NBLK; i += 256) { s += ps[i]; q += pq[i]; }
#pragma unroll
    for (int off = 32; off >= 1; off >>= 1) {
        s += __shfl_xor(s, off);
        q += __shfl_xor(q, off);
    }
    if ((t & 63) == 0) { sh[t >> 6] = s; sh[4 + (t >> 6)] = q; }
    __syncthreads();
    if (t == 0) {
        float S = sh[0] + sh[1] + sh[2] + sh[3];
        float Q = sh[4] + sh[5] + sh[6] + sh[7];
        float mean = S / (float)N_NODES;
        float var = fmaxf(Q / (float)N_NODES - mean * mean, 0.f);
        float scale = gamma[c] * rsqrtf(var + EPSV);
        stats[c] = scale;
        stats[128 + c] = beta[c] - mean * scale;
    }
}

// ---------------- K6: h = relu(h2*scale + shift + h_prev) ----------------
template<bool LAST>
__global__ __launch_bounds__(256) void k_bn_apply(
    const unsigned short* __restrict__ h2b, const float* __restrict__ stats,
    unsigned short* __restrict__ hb, float* __restrict__ h)
{
    __shared__ float ssc[H], ssh[H];
    int tid = threadIdx.x;
    if (tid < H) {
        ssc[tid] = stats[tid];
        ssh[tid] = stats[128 + tid];
    }
    __syncthreads();
    size_t base = ((size_t)blockIdx.x * 256 + tid) * 8;
    int c = (int)(base & 127);
    uint4 hv2 = *(const uint4*)(h2b + base);
    uint4 hvp = *(const uint4*)(hb + base);
    unsigned int u2[4] = {hv2.x, hv2.y, hv2.z, hv2.w};
    unsigned int up[4] = {hvp.x, hvp.y, hvp.z, hvp.w};
    float o[8];
#pragma unroll
    for (int k = 0; k < 4; ++k) {
        float vlo = bf2f(u2[k] & 0xffffu), vhi = bf2f(u2[k] >> 16);
        float plo = bf2f(up[k] & 0xffffu), phi = bf2f(up[k] >> 16);
        o[2 * k]     = fmaxf(vlo * ssc[c + 2 * k]     + ssh[c + 2 * k]     + plo, 0.f);
        o[2 * k + 1] = fmaxf(vhi * ssc[c + 2 * k + 1] + ssh[c + 2 * k + 1] + phi, 0.f);
    }
    uint4 pk;
    pk.x = (unsigned int)f2bf(o[0]) | ((unsigned int)f2bf(o[1]) << 16);
    pk.y = (unsigned int)f2bf(o[2]) | ((unsigned int)f2bf(o[3]) << 16);
    pk.z = (unsigned int)f2bf(o[4]) | ((unsigned int)f2bf(o[5]) << 16);
    pk.w = (unsigned int)f2bf(o[6]) | ((unsigned int)f2bf(o[7]) << 16);
    *(uint4*)(hb + base) = pk;
    if (LAST) {
        *(float4*)(h + base)     = make_float4(o[0], o[1], o[2], o[3]);
        *(float4*)(h + base + 4) = make_float4(o[4], o[5], o[6], o[7]);
    }
}

// ---------------- K7: fused gate MFMA + segment softmax + weighted pool ----------------
// block = 1 graph = 64 nodes, 256 threads (4 waves)
__global__ __launch_bounds__(256) void k_gate_pool(
    const unsigned short* __restrict__ hb, const float* __restrict__ h,
    const unsigned short* __restrict__ gwp,
    const float* __restrict__ b1, const float* __restrict__ w2,
    const float* __restrict__ b2, float* __restrict__ pooled)
{
    __shared__ float Red[256];
    __shared__ float al[64];
    int tid = threadIdx.x;
    int w = tid >> 6, l = tid & 63;
    int lr = l & 15, hi = l >> 4;
    int g = blockIdx.x;
    int n0 = g * SEG;

    f32x4 acc[4][2];
#pragma unroll
    for (int rb = 0; rb < 4; ++rb) {
        acc[rb][0] = (f32x4){0.f, 0.f, 0.f, 0.f};
        acc[rb][1] = (f32x4){0.f, 0.f, 0.f, 0.f};
    }
    const bf16x8* wv = (const bf16x8*)gwp;
#pragma unroll
    for (int ks = 0; ks < 4; ++ks) {
        bf16x8 bb0 = wv[((2 * w + 0) * 4 + ks) * 64 + l];
        bf16x8 bb1 = wv[((2 * w + 1) * 4 + ks) * 64 + l];
#pragma unroll
        for (int rb = 0; rb < 4; ++rb) {
            bf16x8 a = *(const bf16x8*)(hb + (size_t)(n0 + rb * 16 + lr) * H + ks * 32 + hi * 8);
            acc[rb][0] = __builtin_amdgcn_mfma_f32_16x16x32_bf16(a, bb0, acc[rb][0], 0, 0, 0);
            acc[rb][1] = __builtin_amdgcn_mfma_f32_16x16x32_bf16(a, bb1, acc[rb][1], 0, 0, 0);
        }
    }
    // gate row-partials: relu(v + b1) . w2 over this wave's 32 cols
    int col0 = w * 32 + lr, col1 = w * 32 + 16 + lr;
    float b10 = b1[col0], b11 = b1[col1];
    float w20 = w2[col0], w21 = w2[col1];
    float p[4][4];
#pragma unroll
    for (int rb = 0; rb < 4; ++rb)
#pragma unroll
        for (int jj = 0; jj < 4; ++jj) {
            float v0 = fmaxf(acc[rb][0][jj] + b10, 0.f);
            float v1 = fmaxf(acc[rb][1][jj] + b11, 0.f);
            float s = v0 * w20 + v1 * w21;
            s += __shfl_xor(s, 1); s += __shfl_xor(s, 2);
            s += __shfl_xor(s, 4); s += __shfl_xor(s, 8);
            p[rb][jj] = s;
        }
    if (lr == 0) {
#pragma unroll
        for (int rb = 0; rb < 4; ++rb)
#pragma unroll
            for (int jj = 0; jj < 4; ++jj)
                Red[w * 64 + rb * 16 + hi * 4 + jj] = p[rb][jj];
    }
    __syncthreads();
    if (tid < 64) {
        float gt = Red[tid] + Red[64 + tid] + Red[128 + tid] + Red[192 + tid] + b2[0];
        float m = gt;
#pragma unroll
        for (int off = 32; off >= 1; off >>= 1) m = fmaxf(m, __shfl_xor(m, off));
        float e = expf(gt - m);
        float s = e;
#pragma unroll
        for (int off = 32; off >= 1; off >>= 1) s += __shfl_xor(s, off);
        al[tid] = e / s;
    }
    __syncthreads();
    // weighted pool over fp32 h
    int c = tid & 127, half = tid >> 7;
    float pp = 0.f;
    const float* hbase = h + (size_t)n0 * H;
    for (int j = half * 32; j < half * 32 + 32; ++j)
        pp += al[j] * hbase[(size_t)j * H + c];
    Red[tid] = pp;
    __syncthreads();
    if (tid < 128) pooled[(size_t)g * H + tid] = Red[tid] + Red[128 + tid];
}

// ---------------- K9: global_embedding = [pooled, gf] @ gi_w + gi_b ----------------
__global__ __launch_bounds__(128) void k_final(
    const float* __restrict__ pooled, const float* __restrict__ gfeat,
    const float* __restrict__ gf_w, const float* __restrict__ gf_b,
    const float* __restrict__ gi_w, const float* __restrict__ gi_b,
    float* __restrict__ out)
{
    int g = blockIdx.x, c = threadIdx.x;
    __shared__ float prow[H], gfs[H];
    prow[c] = pooled[(size_t)g * H + c];
    float gv = gf_b[c];
    const float* gr = gfeat + (size_t)g * GF;
#pragma unroll
    for (int k = 0; k < GF; ++k) gv += gr[k] * gf_w[k * H + c];
    gfs[c] = gv;
    __syncthreads();
    float acc = gi_b[c];
    for (int k = 0; k < H; ++k) acc += prow[k] * gi_w[k * H + c];
    for (int k = 0; k < H; ++k) acc += gfs[k] * gi_w[(H + k) * H + c];
    out[(size_t)N_NODES * H + (size_t)g * H + c] = acc;
}

extern "C" void kernel_launch(void* const* d_in, const int* in_sizes, int n_in,
                              void* d_out, int out_size, void* d_ws, size_t ws_size,
                              hipStream_t stream)
{
    const float* x       = (const float*)d_in[0];
    const int*   ei      = (const int*)d_in[1];
    const float* eattr   = (const float*)d_in[2];
    const float* gfeat   = (const float*)d_in[3];
    // d_in[4] = batch (unused; batch[n] == n/64)
    const float* node_w  = (const float*)d_in[5];
    const float* node_b  = (const float*)d_in[6];
    const float* edge_w  = (const float*)d_in[7];
    const float* edge_b  = (const float*)d_in[8];
    const float* rel_w   = (const float*)d_in[9];
    const float* rel_b   = (const float*)d_in[10];
    const float* root_w  = (const float*)d_in[11];
    const float* bn_g    = (const float*)d_in[12];
    const float* bn_b    = (const float*)d_in[13];
    const float* gate_w1 = (const float*)d_in[14];
    const float* gate_b1 = (const float*)d_in[15];
    const float* gate_w2 = (const float*)d_in[16];
    const float* gate_b2 = (const float*)d_in[17];
    const float* gf_w    = (const float*)d_in[18];
    const float* gf_b    = (const float*)d_in[19];
    const float* gi_w    = (const float*)d_in[20];
    const float* gi_b    = (const float*)d_in[21];

    float* h   = (float*)d_out;                          // [N,H] output 0 (written by last layer)
    float* out = (float*)d_out;

    char* wsb = (char*)d_ws;
    size_t off = 0;
    auto take = [&](size_t bytes) -> char* {
        char* r = wsb + off;
        off = (off + bytes + 63) & ~(size_t)63;
        return r;
    };
    unsigned short* h2b  = (unsigned short*)take((size_t)N_NODES * H * 2);
    unsigned short* hb   = (unsigned short*)take((size_t)N_NODES * H * 2);
    unsigned short* aggb = (unsigned short*)take((size_t)N_NODES * H * 2);
    unsigned short* wpck = (unsigned short*)take((size_t)LAYERS * 32768 * 2);
    unsigned short* gwp  = (unsigned short*)take((size_t)16384 * 2);
    float* pbuf   = (float*)take((size_t)256 * NBLK * 4);   // BN partials [256][NBLK]
    float* stats  = (float*)take((size_t)256 * 4);          // scale[128], shift[128]
    float* pooled = (float*)take((size_t)N_GRAPH * H * 4);
    int*   deg    = (int*)take((size_t)N_NODES * 4);
    int*   rowptr = (int*)take((size_t)(N_NODES + 1) * 4);
    int*   cursor = (int*)take((size_t)N_NODES * 4);
    int*   bsum   = (int*)take((size_t)NB_SCAN * 4);
    int*   boff   = (int*)take((size_t)NB_SCAN * 4);
    uint4* recs   = (uint4*)take((size_t)N_EDGES * 32);  // {src, ea0..4, pad2} per edge
    int*   rowtmp = cursor;   // alias ok (scan3 reads then writes same idx)

    // ---- CSR build + weight repack (once per launch) ----
    hipMemsetAsync(deg, 0, N_NODES * sizeof(int), stream);
    k_deg<<<(N_EDGES + 255) / 256, 256, 0, stream>>>(ei, deg);
    k_scan1<<<NB_SCAN, 256, 0, stream>>>(deg, rowtmp, bsum);
    k_scan2<<<1, 256, 0, stream>>>(bsum, boff);
    k_scan3<<<NB_SCAN, 256, 0, stream>>>(rowtmp, boff, rowptr, cursor);
    k_scatter<<<(N_EDGES + 255) / 256, 256, 0, stream>>>(ei, eattr, cursor, recs);
    k_wpack<<<LAYERS * 64, 64, 0, stream>>>(rel_w, root_w, wpck);
    k_wpack_gate<<<32, 64, 0, stream>>>(gate_w1, gwp);

    k_init_h<<<N_NODES * 16 / 256, 256, 0, stream>>>(x, node_w, node_b, hb);

    for (int i = 0; i < LAYERS; ++i) {
        k_agg<<<N_NODES / 16, 256, 0, stream>>>(rowptr, recs, edge_w, edge_b, hb, aggb);
        k_gemm_mfma<<<NBLK, 256, 0, stream>>>(
            aggb, hb, wpck + (size_t)i * 32768, rel_b + (size_t)i * H,
            h2b, pbuf);
        k_red<<<128, 256, 0, stream>>>(pbuf, bn_g + (size_t)i * H, bn_b + (size_t)i * H, stats);
        if (i < LAYERS - 1)
            k_bn_apply<false><<<N_NODES * H / 8 / 256, 256, 0, stream>>>(h2b, stats, hb, h);
        else
            k_bn_apply<true><<<N_NODES * H / 8 / 256, 256, 0, stream>>>(h2b, stats, hb, h);
    }

    k_gate_pool<<<N_GRAPH, 256, 0, stream>>>(hb, h, gwp, gate_b1, gate_w2, gate_b2, pooled);
    k_final<<<N_GRAPH, H, 0, stream>>>(pooled, gfeat, gf_w, gf_b, gi_w, gi_b, out);
}

// Round 11
// 1036.663 us; speedup vs baseline: 1.0717x; 1.0717x over previous
//
#include <hip/hip_runtime.h>
#include <math.h>

#define N_NODES 204800
#define N_EDGES 600000
#define N_GRAPH 3200
#define H 128
#define NF 16
#define EF 5
#define GF 8
#define LAYERS 6
#define SEG 64
#define EPSV 1e-5f
#define NB_SCAN 800   // N_NODES / 256
#define NBLK 3200     // N_NODES / 64 (gemm blocks)

typedef __attribute__((ext_vector_type(8))) short bf16x8;
typedef __attribute__((ext_vector_type(4))) float f32x4;

__device__ inline float bf2f(unsigned int u) {            // low 16 bits = bf16
    return __builtin_bit_cast(float, u << 16);
}
__device__ inline unsigned short f2bf(float f) {          // RNE
    unsigned int u = __builtin_bit_cast(unsigned int, f);
    u += 0x7fffu + ((u >> 16) & 1u);
    return (unsigned short)(u >> 16);
}
__device__ inline float uif(unsigned int u) { return __builtin_bit_cast(float, u); }

// ---------------- K1: hb = bf16(x @ node_w + node_b) ----------------
// 16 threads/node, 8 outputs/thread, vectorized x loads.
__global__ __launch_bounds__(256) void k_init_h(
    const float* __restrict__ x, const float* __restrict__ node_w,
    const float* __restrict__ node_b, unsigned short* __restrict__ hb)
{
    int idx = blockIdx.x * 256 + threadIdx.x;   // n*16 + c8
    int n = idx >> 4, c0 = (idx & 15) * 8;
    const float4* xr = (const float4*)(x + (size_t)n * NF);
    float4 x0 = xr[0], x1 = xr[1], x2 = xr[2], x3 = xr[3];
    float xa[16] = {x0.x, x0.y, x0.z, x0.w, x1.x, x1.y, x1.z, x1.w,
                    x2.x, x2.y, x2.z, x2.w, x3.x, x3.y, x3.z, x3.w};
    float4 a0 = *(const float4*)(node_b + c0);
    float4 a1 = *(const float4*)(node_b + c0 + 4);
#pragma unroll
    for (int k = 0; k < NF; ++k) {
        float xv = xa[k];
        float4 w0 = *(const float4*)(node_w + k * H + c0);
        float4 w1 = *(const float4*)(node_w + k * H + c0 + 4);
        a0.x += xv * w0.x; a0.y += xv * w0.y; a0.z += xv * w0.z; a0.w += xv * w0.w;
        a1.x += xv * w1.x; a1.y += xv * w1.y; a1.z += xv * w1.z; a1.w += xv * w1.w;
    }
    uint4 pk;
    pk.x = (unsigned int)f2bf(a0.x) | ((unsigned int)f2bf(a0.y) << 16);
    pk.y = (unsigned int)f2bf(a0.z) | ((unsigned int)f2bf(a0.w) << 16);
    pk.z = (unsigned int)f2bf(a1.x) | ((unsigned int)f2bf(a1.y) << 16);
    pk.w = (unsigned int)f2bf(a1.z) | ((unsigned int)f2bf(a1.w) << 16);
    *(uint4*)(hb + (size_t)n * H + c0) = pk;
}

// ---------------- W repack: [rel|root] -> MFMA B-fragment order, bf16 ----------------
// wp[i][nb(8)][ks(8)][lane(64)][8]  ; ks 0..3 = rel (agg half), 4..7 = root (h half)
__global__ __launch_bounds__(64) void k_wpack(
    const float* __restrict__ relw, const float* __restrict__ rootw,
    unsigned short* __restrict__ wp)
{
    int bid = blockIdx.x;          // i*64 + nb*8 + ks
    int i = bid >> 6, f = bid & 63;
    int nb = f >> 3, ks = f & 7;
    int l = threadIdx.x;
    const float* src = (ks < 4) ? (relw + (size_t)i * H * H) : (rootw + (size_t)i * H * H);
    int ksl = ks & 3;
    int col = nb * 16 + (l & 15);
    int kbase = ksl * 32 + (l >> 4) * 8;
    unsigned short tmp[8];
#pragma unroll
    for (int m = 0; m < 8; ++m)
        tmp[m] = f2bf(src[(size_t)(kbase + m) * H + col]);
    *(uint4*)(wp + ((size_t)bid * 64 + l) * 8) = *(uint4*)tmp;
}

// gate_w1 pack: gwp[nb(8)][ks(4)][lane(64)][8]
__global__ __launch_bounds__(64) void k_wpack_gate(
    const float* __restrict__ gw1, unsigned short* __restrict__ gwp)
{
    int bid = blockIdx.x;          // nb*4 + ks
    int nb = bid >> 2, ks = bid & 3;
    int l = threadIdx.x;
    int col = nb * 16 + (l & 15);
    int kbase = ks * 32 + (l >> 4) * 8;
    unsigned short tmp[8];
#pragma unroll
    for (int m = 0; m < 8; ++m)
        tmp[m] = f2bf(gw1[(size_t)(kbase + m) * H + col]);
    *(uint4*)(gwp + ((size_t)bid * 64 + l) * 8) = *(uint4*)tmp;
}

// ---------------- CSR build: deg -> scan -> scatter ----------------
__global__ __launch_bounds__(256) void k_deg(const int* __restrict__ ei, int* __restrict__ deg)
{
    int e = blockIdx.x * 256 + threadIdx.x;
    if (e < N_EDGES) atomicAdd(&deg[ei[N_EDGES + e]], 1);
}

__global__ __launch_bounds__(256) void k_scan1(
    const int* __restrict__ deg, int* __restrict__ rowtmp, int* __restrict__ bsum)
{
    __shared__ int sh[256];
    int t = threadIdx.x;
    int i = blockIdx.x * 256 + t;
    int v = deg[i];
    sh[t] = v;
    __syncthreads();
    for (int off = 1; off < 256; off <<= 1) {
        int a = (t >= off) ? sh[t - off] : 0;
        __syncthreads();
        sh[t] += a;
        __syncthreads();
    }
    rowtmp[i] = sh[t] - v;                 // exclusive
    if (t == 255) bsum[blockIdx.x] = sh[255];
}

__global__ void k_scan2(int* __restrict__ bsum, int* __restrict__ boff)  // 1 block x 256
{
    __shared__ int sh[256];
    __shared__ int carry;
    int t = threadIdx.x;
    if (t == 0) carry = 0;
    __syncthreads();
    for (int base = 0; base < NB_SCAN; base += 256) {
        int i = base + t;
        int v = (i < NB_SCAN) ? bsum[i] : 0;
        sh[t] = v;
        __syncthreads();
        for (int off = 1; off < 256; off <<= 1) {
            int a = (t >= off) ? sh[t - off] : 0;
            __syncthreads();
            sh[t] += a;
            __syncthreads();
        }
        if (i < NB_SCAN) boff[i] = carry + sh[t] - v;
        __syncthreads();
        if (t == 0) carry += sh[255];
        __syncthreads();
    }
}

__global__ __launch_bounds__(256) void k_scan3(
    const int* __restrict__ rowtmp, const int* __restrict__ boff,
    int* __restrict__ rowptr, int* __restrict__ cursor)
{
    int i = blockIdx.x * 256 + threadIdx.x;
    int r = rowtmp[i] + boff[blockIdx.x];
    rowptr[i] = r;
    cursor[i] = r;
    if (i == 0) rowptr[N_NODES] = N_EDGES;
}

// scatter 32B records: {src, ea0..ea4, pad, pad}
__global__ __launch_bounds__(256) void k_scatter(
    const int* __restrict__ ei, const float* __restrict__ eattr,
    int* __restrict__ cursor, uint4* __restrict__ recs)
{
    int e = blockIdx.x * 256 + threadIdx.x;
    if (e >= N_EDGES) return;
    int d = ei[N_EDGES + e];
    const float* ar = eattr + (size_t)e * EF;
    float c0 = ar[0], c1 = ar[1], c2 = ar[2], c3 = ar[3], c4 = ar[4];
    int pos = atomicAdd(&cursor[d], 1);
    uint4 q0, q1;
    q0.x = (unsigned int)ei[e];
    q0.y = __builtin_bit_cast(unsigned int, c0);
    q0.z = __builtin_bit_cast(unsigned int, c1);
    q0.w = __builtin_bit_cast(unsigned int, c2);
    q1.x = __builtin_bit_cast(unsigned int, c3);
    q1.y = __builtin_bit_cast(unsigned int, c4);
    q1.z = 0; q1.w = 0;
    recs[2 * (size_t)pos]     = q0;
    recs[2 * (size_t)pos + 1] = q1;
}

// ---------------- K3: pull aggregation; 2 nodes/wave, interleaved 2-edge unroll --------
// (round-9 proven-best variant: data-dependent trip counts, 4 gathers in flight)
#define EDGE_ONE(q0, q1, A0, A1)                                               \
    {                                                                          \
        unsigned int hv = *(const unsigned int*)(hb + (size_t)(int)(q0).x * H + 2 * l); \
        float ea0 = eb2.x, ea1 = eb2.y;                                        \
        float c0 = uif((q0).y), c1 = uif((q0).z), c2 = uif((q0).w);            \
        float c3 = uif((q1).x), c4 = uif((q1).y);                              \
        ea0 += c0 * ew2[0].x + c1 * ew2[1].x + c2 * ew2[2].x + c3 * ew2[3].x + c4 * ew2[4].x; \
        ea1 += c0 * ew2[0].y + c1 * ew2[1].y + c2 * ew2[2].y + c3 * ew2[3].y + c4 * ew2[4].y; \
        A0 += bf2f(hv & 0xffffu) * ea0;                                        \
        A1 += bf2f(hv >> 16) * ea1;                                            \
    }

__global__ __launch_bounds__(256) void k_agg(
    const int* __restrict__ rowptr, const uint4* __restrict__ recs,
    const float* __restrict__ edge_w, const float* __restrict__ edge_b,
    const unsigned short* __restrict__ hb, unsigned short* __restrict__ aggb)
{
    int w = threadIdx.x >> 6, l = threadIdx.x & 63;
    int n = blockIdx.x * 8 + w * 2;            // this wave: nodes n, n+1
    float2 ew2[EF];
#pragma unroll
    for (int k = 0; k < EF; ++k) ew2[k] = ((const float2*)(edge_w + k * H))[l];
    float2 eb2 = ((const float2*)edge_b)[l];

    int jA = rowptr[n], eA = rowptr[n + 1];
    int jB = eA,        eB = rowptr[n + 2];
    float a0 = 0.f, a1 = 0.f, b0 = 0.f, b1 = 0.f;

    // interleaved main loop: 4 independent gathers in flight
    while (jA + 2 <= eA && jB + 2 <= eB) {
        uint4 qa0 = recs[2 * jA],     qa1 = recs[2 * jA + 1];
        uint4 qb0 = recs[2 * jA + 2], qb1 = recs[2 * jA + 3];
        uint4 qc0 = recs[2 * jB],     qc1 = recs[2 * jB + 1];
        uint4 qd0 = recs[2 * jB + 2], qd1 = recs[2 * jB + 3];
        EDGE_ONE(qa0, qa1, a0, a1);
        EDGE_ONE(qb0, qb1, a0, a1);
        EDGE_ONE(qc0, qc1, b0, b1);
        EDGE_ONE(qd0, qd1, b0, b1);
        jA += 2; jB += 2;
    }
    // drain A
    while (jA + 2 <= eA) {
        uint4 qa0 = recs[2 * jA],     qa1 = recs[2 * jA + 1];
        uint4 qb0 = recs[2 * jA + 2], qb1 = recs[2 * jA + 3];
        EDGE_ONE(qa0, qa1, a0, a1);
        EDGE_ONE(qb0, qb1, a0, a1);
        jA += 2;
    }
    if (jA < eA) {
        uint4 qa0 = recs[2 * jA], qa1 = recs[2 * jA + 1];
        EDGE_ONE(qa0, qa1, a0, a1);
    }
    // drain B
    while (jB + 2 <= eB) {
        uint4 qc0 = recs[2 * jB],     qc1 = recs[2 * jB + 1];
        uint4 qd0 = recs[2 * jB + 2], qd1 = recs[2 * jB + 3];
        EDGE_ONE(qc0, qc1, b0, b1);
        EDGE_ONE(qd0, qd1, b0, b1);
        jB += 2;
    }
    if (jB < eB) {
        uint4 qc0 = recs[2 * jB], qc1 = recs[2 * jB + 1];
        EDGE_ONE(qc0, qc1, b0, b1);
    }

    unsigned int pka = (unsigned int)f2bf(a0) | ((unsigned int)f2bf(a1) << 16);
    unsigned int pkb = (unsigned int)f2bf(b0) | ((unsigned int)f2bf(b1) << 16);
    *(unsigned int*)(aggb + (size_t)n * H + 2 * l)       = pka;
    *(unsigned int*)(aggb + (size_t)(n + 1) * H + 2 * l) = pkb;
}

// ---------------- K4: MFMA dual-GEMM, A in swizzled LDS; BN partials -> pbuf (no atomics)
// block = 256 (4 waves); tile 64 rows x 128 cols; wave w: cols [w*32, w*32+32)
__global__ __launch_bounds__(256) void k_gemm_mfma(
    const unsigned short* __restrict__ aggb,
    const unsigned short* __restrict__ hb,
    const unsigned short* __restrict__ wp,      // this layer's 64KB packed [rel|root]
    const float* __restrict__ relb,
    unsigned short* __restrict__ h2b,
    float* __restrict__ pbuf)                   // [256][NBLK] per-block partials
{
    __shared__ unsigned short smA[64 * 128];    // 16KB agg tile (swizzled)
    __shared__ unsigned short smH[64 * 128];    // 16KB h tile (swizzled)
    int tid = threadIdx.x;
    int w = tid >> 6, l = tid & 63;
    int bid = blockIdx.x;
    int n0 = bid * 64;
    int lr = l & 15, hi = l >> 4;

    // ---- stage both A tiles: coalesced global read, swizzled LDS write ----
    const char* aggp = (const char*)(aggb + (size_t)n0 * H);
    const char* hbp  = (const char*)(hb  + (size_t)n0 * H);
    char* sA = (char*)smA;
    char* sH = (char*)smH;
#pragma unroll
    for (int i = 0; i < 4; ++i) {
        int o = (i * 256 + tid) * 16;           // linear byte offset in 16KB tile
        int row = o >> 8;                       // /256B per row
        int col = o & 255;
        int scol = col ^ ((row & 7) << 4);
        uint4 va = *(const uint4*)(aggp + o);
        uint4 vh = *(const uint4*)(hbp + o);
        *(uint4*)(sA + row * 256 + scol) = va;
        *(uint4*)(sH + row * 256 + scol) = vh;
    }
    __syncthreads();

    f32x4 acc[4][2];
#pragma unroll
    for (int rb = 0; rb < 4; ++rb) {
        acc[rb][0] = (f32x4){0.f, 0.f, 0.f, 0.f};
        acc[rb][1] = (f32x4){0.f, 0.f, 0.f, 0.f};
    }

    const bf16x8* wv = (const bf16x8*)wp;
#pragma unroll
    for (int ks = 0; ks < 4; ++ks) {            // agg half: A from LDS
        bf16x8 b0 = wv[((2 * w + 0) * 8 + ks) * 64 + l];
        bf16x8 b1 = wv[((2 * w + 1) * 8 + ks) * 64 + l];
#pragma unroll
        for (int rb = 0; rb < 4; ++rb) {
            int r = rb * 16 + lr;
            int bc = (ks * 64 + hi * 16) ^ ((r & 7) << 4);
            bf16x8 a = *(const bf16x8*)(sA + r * 256 + bc);
            acc[rb][0] = __builtin_amdgcn_mfma_f32_16x16x32_bf16(a, b0, acc[rb][0], 0, 0, 0);
            acc[rb][1] = __builtin_amdgcn_mfma_f32_16x16x32_bf16(a, b1, acc[rb][1], 0, 0, 0);
        }
    }
#pragma unroll
    for (int ks = 0; ks < 4; ++ks) {            // root half: A from LDS
        bf16x8 b0 = wv[((2 * w + 0) * 8 + 4 + ks) * 64 + l];
        bf16x8 b1 = wv[((2 * w + 1) * 8 + 4 + ks) * 64 + l];
#pragma unroll
        for (int rb = 0; rb < 4; ++rb) {
            int r = rb * 16 + lr;
            int bc = (ks * 64 + hi * 16) ^ ((r & 7) << 4);
            bf16x8 a = *(const bf16x8*)(sH + r * 256 + bc);
            acc[rb][0] = __builtin_amdgcn_mfma_f32_16x16x32_bf16(a, b0, acc[rb][0], 0, 0, 0);
            acc[rb][1] = __builtin_amdgcn_mfma_f32_16x16x32_bf16(a, b1, acc[rb][1], 0, 0, 0);
        }
    }

    // epilogue: bias, bf16 store, per-block BN partials (plain stores, no atomics)
#pragma unroll
    for (int nbl = 0; nbl < 2; ++nbl) {
        int col = w * 32 + nbl * 16 + lr;
        float bs = relb[col];
        float csum = 0.f, csq = 0.f;
#pragma unroll
        for (int rb = 0; rb < 4; ++rb) {
#pragma unroll
            for (int jj = 0; jj < 4; ++jj) {
                float v = acc[rb][nbl][jj] + bs;
                h2b[(size_t)(n0 + rb * 16 + hi * 4 + jj) * H + col] = f2bf(v);
                csum += v; csq += v * v;
            }
        }
        csum += __shfl_xor(csum, 16); csum += __shfl_xor(csum, 32);
        csq  += __shfl_xor(csq, 16);  csq  += __shfl_xor(csq, 32);
        if (hi == 0) {
            pbuf[(size_t)col * NBLK + bid]         = csum;
            pbuf[(size_t)(128 + col) * NBLK + bid] = csq;
        }
    }
}

// ---------------- K5: reduce pbuf -> scale/shift (one block per column) ----------------
__global__ __launch_bounds__(256) void k_red(
    const float* __restrict__ pbuf, const float* __restrict__ gamma,
    const float* __restrict__ beta, float* __restrict__ stats)
{
    __shared__ float sh[8];
    int c = blockIdx.x;                 // 0..127
    int t = threadIdx.x;
    float s = 0.f, q = 0.f;
    const float* ps = pbuf + (size_t)c * NBLK;
    const float* pq = pbuf + (size_t)(128 + c) * NBLK;
    for (int i = t; i < NBLK; i += 256) { s += ps[i]; q += pq[i]; }
#pragma unroll
    for (int off = 32; off >= 1; off >>= 1) {
        s += __shfl_xor(s, off);
        q += __shfl_xor(q, off);
    }
    if ((t & 63) == 0) { sh[t >> 6] = s; sh[4 + (t >> 6)] = q; }
    __syncthreads();
    if (t == 0) {
        float S = sh[0] + sh[1] + sh[2] + sh[3];
        float Q = sh[4] + sh[5] + sh[6] + sh[7];
        float mean = S / (float)N_NODES;
        float var = fmaxf(Q / (float)N_NODES - mean * mean, 0.f);
        float scale = gamma[c] * rsqrtf(var + EPSV);
        stats[c] = scale;
        stats[128 + c] = beta[c] - mean * scale;
    }
}

// ---------------- K6: h = relu(h2*scale + shift + h_prev) ----------------
template<bool LAST>
__global__ __launch_bounds__(256) void k_bn_apply(
    const unsigned short* __restrict__ h2b, const float* __restrict__ stats,
    unsigned short* __restrict__ hb, float* __restrict__ h)
{
    __shared__ float ssc[H], ssh[H];
    int tid = threadIdx.x;
    if (tid < H) {
        ssc[tid] = stats[tid];
        ssh[tid] = stats[128 + tid];
    }
    __syncthreads();
    size_t base = ((size_t)blockIdx.x * 256 + tid) * 8;
    int c = (int)(base & 127);
    uint4 hv2 = *(const uint4*)(h2b + base);
    uint4 hvp = *(const uint4*)(hb + base);
    unsigned int u2[4] = {hv2.x, hv2.y, hv2.z, hv2.w};
    unsigned int up[4] = {hvp.x, hvp.y, hvp.z, hvp.w};
    float o[8];
#pragma unroll
    for (int k = 0; k < 4; ++k) {
        float vlo = bf2f(u2[k] & 0xffffu), vhi = bf2f(u2[k] >> 16);
        float plo = bf2f(up[k] & 0xffffu), phi = bf2f(up[k] >> 16);
        o[2 * k]     = fmaxf(vlo * ssc[c + 2 * k]     + ssh[c + 2 * k]     + plo, 0.f);
        o[2 * k + 1] = fmaxf(vhi * ssc[c + 2 * k + 1] + ssh[c + 2 * k + 1] + phi, 0.f);
    }
    uint4 pk;
    pk.x = (unsigned int)f2bf(o[0]) | ((unsigned int)f2bf(o[1]) << 16);
    pk.y = (unsigned int)f2bf(o[2]) | ((unsigned int)f2bf(o[3]) << 16);
    pk.z = (unsigned int)f2bf(o[4]) | ((unsigned int)f2bf(o[5]) << 16);
    pk.w = (unsigned int)f2bf(o[6]) | ((unsigned int)f2bf(o[7]) << 16);
    *(uint4*)(hb + base) = pk;
    if (LAST) {
        *(float4*)(h + base)     = make_float4(o[0], o[1], o[2], o[3]);
        *(float4*)(h + base + 4) = make_float4(o[4], o[5], o[6], o[7]);
    }
}

// ---------------- K7: fused gate MFMA + segment softmax + weighted pool ----------------
// block = 1 graph = 64 nodes, 256 threads (4 waves)
__global__ __launch_bounds__(256) void k_gate_pool(
    const unsigned short* __restrict__ hb, const float* __restrict__ h,
    const unsigned short* __restrict__ gwp,
    const float* __restrict__ b1, const float* __restrict__ w2,
    const float* __restrict__ b2, float* __restrict__ pooled)
{
    __shared__ float Red[256];
    __shared__ float al[64];
    int tid = threadIdx.x;
    int w = tid >> 6, l = tid & 63;
    int lr = l & 15, hi = l >> 4;
    int g = blockIdx.x;
    int n0 = g * SEG;

    f32x4 acc[4][2];
#pragma unroll
    for (int rb = 0; rb < 4; ++rb) {
        acc[rb][0] = (f32x4){0.f, 0.f, 0.f, 0.f};
        acc[rb][1] = (f32x4){0.f, 0.f, 0.f, 0.f};
    }
    const bf16x8* wv = (const bf16x8*)gwp;
#pragma unroll
    for (int ks = 0; ks < 4; ++ks) {
        bf16x8 bb0 = wv[((2 * w + 0) * 4 + ks) * 64 + l];
        bf16x8 bb1 = wv[((2 * w + 1) * 4 + ks) * 64 + l];
#pragma unroll
        for (int rb = 0; rb < 4; ++rb) {
            bf16x8 a = *(const bf16x8*)(hb + (size_t)(n0 + rb * 16 + lr) * H + ks * 32 + hi * 8);
            acc[rb][0] = __builtin_amdgcn_mfma_f32_16x16x32_bf16(a, bb0, acc[rb][0], 0, 0, 0);
            acc[rb][1] = __builtin_amdgcn_mfma_f32_16x16x32_bf16(a, bb1, acc[rb][1], 0, 0, 0);
        }
    }
    // gate row-partials: relu(v + b1) . w2 over this wave's 32 cols
    int col0 = w * 32 + lr, col1 = w * 32 + 16 + lr;
    float b10 = b1[col0], b11 = b1[col1];
    float w20 = w2[col0], w21 = w2[col1];
    float p[4][4];
#pragma unroll
    for (int rb = 0; rb < 4; ++rb)
#pragma unroll
        for (int jj = 0; jj < 4; ++jj) {
            float v0 = fmaxf(acc[rb][0][jj] + b10, 0.f);
            float v1 = fmaxf(acc[rb][1][jj] + b11, 0.f);
            float s = v0 * w20 + v1 * w21;
            s += __shfl_xor(s, 1); s += __shfl_xor(s, 2);
            s += __shfl_xor(s, 4); s += __shfl_xor(s, 8);
            p[rb][jj] = s;
        }
    if (lr == 0) {
#pragma unroll
        for (int rb = 0; rb < 4; ++rb)
#pragma unroll
            for (int jj = 0; jj < 4; ++jj)
                Red[w * 64 + rb * 16 + hi * 4 + jj] = p[rb][jj];
    }
    __syncthreads();
    if (tid < 64) {
        float gt = Red[tid] + Red[64 + tid] + Red[128 + tid] + Red[192 + tid] + b2[0];
        float m = gt;
#pragma unroll
        for (int off = 32; off >= 1; off >>= 1) m = fmaxf(m, __shfl_xor(m, off));
        float e = expf(gt - m);
        float s = e;
#pragma unroll
        for (int off = 32; off >= 1; off >>= 1) s += __shfl_xor(s, off);
        al[tid] = e / s;
    }
    __syncthreads();
    // weighted pool over fp32 h
    int c = tid & 127, half = tid >> 7;
    float pp = 0.f;
    const float* hbase = h + (size_t)n0 * H;
    for (int j = half * 32; j < half * 32 + 32; ++j)
        pp += al[j] * hbase[(size_t)j * H + c];
    Red[tid] = pp;
    __syncthreads();
    if (tid < 128) pooled[(size_t)g * H + tid] = Red[tid] + Red[128 + tid];
}

// ---------------- K9: global_embedding = [pooled, gf] @ gi_w + gi_b ----------------
__global__ __launch_bounds__(128) void k_final(
    const float* __restrict__ pooled, const float* __restrict__ gfeat,
    const float* __restrict__ gf_w, const float* __restrict__ gf_b,
    const float* __restrict__ gi_w, const float* __restrict__ gi_b,
    float* __restrict__ out)
{
    int g = blockIdx.x, c = threadIdx.x;
    __shared__ float prow[H], gfs[H];
    prow[c] = pooled[(size_t)g * H + c];
    float gv = gf_b[c];
    const float* gr = gfeat + (size_t)g * GF;
#pragma unroll
    for (int k = 0; k < GF; ++k) gv += gr[k] * gf_w[k * H + c];
    gfs[c] = gv;
    __syncthreads();
    float acc = gi_b[c];
    for (int k = 0; k < H; ++k) acc += prow[k] * gi_w[k * H + c];
    for (int k = 0; k < H; ++k) acc += gfs[k] * gi_w[(H + k) * H + c];
    out[(size_t)N_NODES * H + (size_t)g * H + c] = acc;
}

extern "C" void kernel_launch(void* const* d_in, const int* in_sizes, int n_in,
                              void* d_out, int out_size, void* d_ws, size_t ws_size,
                              hipStream_t stream)
{
    const float* x       = (const float*)d_in[0];
    const int*   ei      = (const int*)d_in[1];
    const float* eattr   = (const float*)d_in[2];
    const float* gfeat   = (const float*)d_in[3];
    // d_in[4] = batch (unused; batch[n] == n/64)
    const float* node_w  = (const float*)d_in[5];
    const float* node_b  = (const float*)d_in[6];
    const float* edge_w  = (const float*)d_in[7];
    const float* edge_b  = (const float*)d_in[8];
    const float* rel_w   = (const float*)d_in[9];
    const float* rel_b   = (const float*)d_in[10];
    const float* root_w  = (const float*)d_in[11];
    const float* bn_g    = (const float*)d_in[12];
    const float* bn_b    = (const float*)d_in[13];
    const float* gate_w1 = (const float*)d_in[14];
    const float* gate_b1 = (const float*)d_in[15];
    const float* gate_w2 = (const float*)d_in[16];
    const float* gate_b2 = (const float*)d_in[17];
    const float* gf_w    = (const float*)d_in[18];
    const float* gf_b    = (const float*)d_in[19];
    const float* gi_w    = (const float*)d_in[20];
    const float* gi_b    = (const float*)d_in[21];

    float* h   = (float*)d_out;                          // [N,H] output 0 (written by last layer)
    float* out = (float*)d_out;

    char* wsb = (char*)d_ws;
    size_t off = 0;
    auto take = [&](size_t bytes) -> char* {
        char* r = wsb + off;
        off = (off + bytes + 63) & ~(size_t)63;
        return r;
    };
    unsigned short* h2b  = (unsigned short*)take((size_t)N_NODES * H * 2);
    unsigned short* hb   = (unsigned short*)take((size_t)N_NODES * H * 2);
    unsigned short* aggb = (unsigned short*)take((size_t)N_NODES * H * 2);
    unsigned short* wpck = (unsigned short*)take((size_t)LAYERS * 32768 * 2);
    unsigned short* gwp  = (unsigned short*)take((size_t)16384 * 2);
    float* pbuf   = (float*)take((size_t)256 * NBLK * 4);   // BN partials [256][NBLK]
    float* stats  = (float*)take((size_t)256 * 4);          // scale[128], shift[128]
    float* pooled = (float*)take((size_t)N_GRAPH * H * 4);
    int*   deg    = (int*)take((size_t)N_NODES * 4);
    int*   rowptr = (int*)take((size_t)(N_NODES + 1) * 4);
    int*   cursor = (int*)take((size_t)N_NODES * 4);
    int*   bsum   = (int*)take((size_t)NB_SCAN * 4);
    int*   boff   = (int*)take((size_t)NB_SCAN * 4);
    uint4* recs   = (uint4*)take((size_t)N_EDGES * 32);  // {src, ea0..4, pad2} per edge
    int*   rowtmp = cursor;   // alias ok (scan3 reads then writes same idx)

    // ---- CSR build + weight repack (once per launch) ----
    hipMemsetAsync(deg, 0, N_NODES * sizeof(int), stream);
    k_deg<<<(N_EDGES + 255) / 256, 256, 0, stream>>>(ei, deg);
    k_scan1<<<NB_SCAN, 256, 0, stream>>>(deg, rowtmp, bsum);
    k_scan2<<<1, 256, 0, stream>>>(bsum, boff);
    k_scan3<<<NB_SCAN, 256, 0, stream>>>(rowtmp, boff, rowptr, cursor);
    k_scatter<<<(N_EDGES + 255) / 256, 256, 0, stream>>>(ei, eattr, cursor, recs);
    k_wpack<<<LAYERS * 64, 64, 0, stream>>>(rel_w, root_w, wpck);
    k_wpack_gate<<<32, 64, 0, stream>>>(gate_w1, gwp);

    k_init_h<<<N_NODES * 16 / 256, 256, 0, stream>>>(x, node_w, node_b, hb);

    for (int i = 0; i < LAYERS; ++i) {
        k_agg<<<N_NODES / 8, 256, 0, stream>>>(rowptr, recs, edge_w, edge_b, hb, aggb);
        k_gemm_mfma<<<NBLK, 256, 0, stream>>>(
            aggb, hb, wpck + (size_t)i * 32768, rel_b + (size_t)i * H,
            h2b, pbuf);
        k_red<<<128, 256, 0, stream>>>(pbuf, bn_g + (size_t)i * H, bn_b + (size_t)i * H, stats);
        if (i < LAYERS - 1)
            k_bn_apply<false><<<N_NODES * H / 8 / 256, 256, 0, stream>>>(h2b, stats, hb, h);
        else
            k_bn_apply<true><<<N_NODES * H / 8 / 256, 256, 0, stream>>>(h2b, stats, hb, h);
    }

    k_gate_pool<<<N_GRAPH, 256, 0, stream>>>(hb, h, gwp, gate_b1, gate_w2, gate_b2, pooled);
    k_final<<<N_GRAPH, H, 0, stream>>>(pooled, gfeat, gf_w, gf_b, gi_w, gi_b, out);
}

// Round 12
// 975.330 us; speedup vs baseline: 1.1391x; 1.0629x over previous
//
#include <hip/hip_runtime.h>
#include <math.h>

#define N_NODES 204800
#define N_EDGES 600000
#define N_GRAPH 3200
#define H 128
#define NF 16
#define EF 5
#define GF 8
#define LAYERS 6
#define SEG 64
#define EPSV 1e-5f
#define NB_SCAN 800   // N_NODES / 256
#define NBLK 3200     // N_NODES / 64 (gemm blocks)

typedef __attribute__((ext_vector_type(8))) short bf16x8;
typedef __attribute__((ext_vector_type(4))) float f32x4;

__device__ inline float bf2f(unsigned int u) {            // low 16 bits = bf16
    return __builtin_bit_cast(float, u << 16);
}
__device__ inline unsigned short f2bf(float f) {          // RNE
    unsigned int u = __builtin_bit_cast(unsigned int, f);
    u += 0x7fffu + ((u >> 16) & 1u);
    return (unsigned short)(u >> 16);
}
__device__ inline float uif(unsigned int u) { return __builtin_bit_cast(float, u); }

// ---------------- K1: hb = bf16(x @ node_w + node_b) ----------------
__global__ __launch_bounds__(256) void k_init_h(
    const float* __restrict__ x, const float* __restrict__ node_w,
    const float* __restrict__ node_b, unsigned short* __restrict__ hb)
{
    int idx = blockIdx.x * 256 + threadIdx.x;   // n*16 + c8
    int n = idx >> 4, c0 = (idx & 15) * 8;
    const float4* xr = (const float4*)(x + (size_t)n * NF);
    float4 x0 = xr[0], x1 = xr[1], x2 = xr[2], x3 = xr[3];
    float xa[16] = {x0.x, x0.y, x0.z, x0.w, x1.x, x1.y, x1.z, x1.w,
                    x2.x, x2.y, x2.z, x2.w, x3.x, x3.y, x3.z, x3.w};
    float4 a0 = *(const float4*)(node_b + c0);
    float4 a1 = *(const float4*)(node_b + c0 + 4);
#pragma unroll
    for (int k = 0; k < NF; ++k) {
        float xv = xa[k];
        float4 w0 = *(const float4*)(node_w + k * H + c0);
        float4 w1 = *(const float4*)(node_w + k * H + c0 + 4);
        a0.x += xv * w0.x; a0.y += xv * w0.y; a0.z += xv * w0.z; a0.w += xv * w0.w;
        a1.x += xv * w1.x; a1.y += xv * w1.y; a1.z += xv * w1.z; a1.w += xv * w1.w;
    }
    uint4 pk;
    pk.x = (unsigned int)f2bf(a0.x) | ((unsigned int)f2bf(a0.y) << 16);
    pk.y = (unsigned int)f2bf(a0.z) | ((unsigned int)f2bf(a0.w) << 16);
    pk.z = (unsigned int)f2bf(a1.x) | ((unsigned int)f2bf(a1.y) << 16);
    pk.w = (unsigned int)f2bf(a1.z) | ((unsigned int)f2bf(a1.w) << 16);
    *(uint4*)(hb + (size_t)n * H + c0) = pk;
}

// ---------------- W repack: [rel|root] -> MFMA B-fragment order, bf16 ----------------
__global__ __launch_bounds__(64) void k_wpack(
    const float* __restrict__ relw, const float* __restrict__ rootw,
    unsigned short* __restrict__ wp)
{
    int bid = blockIdx.x;          // i*64 + nb*8 + ks
    int i = bid >> 6, f = bid & 63;
    int nb = f >> 3, ks = f & 7;
    int l = threadIdx.x;
    const float* src = (ks < 4) ? (relw + (size_t)i * H * H) : (rootw + (size_t)i * H * H);
    int ksl = ks & 3;
    int col = nb * 16 + (l & 15);
    int kbase = ksl * 32 + (l >> 4) * 8;
    unsigned short tmp[8];
#pragma unroll
    for (int m = 0; m < 8; ++m)
        tmp[m] = f2bf(src[(size_t)(kbase + m) * H + col]);
    *(uint4*)(wp + ((size_t)bid * 64 + l) * 8) = *(uint4*)tmp;
}

// gate_w1 pack: gwp[nb(8)][ks(4)][lane(64)][8]
__global__ __launch_bounds__(64) void k_wpack_gate(
    const float* __restrict__ gw1, unsigned short* __restrict__ gwp)
{
    int bid = blockIdx.x;          // nb*4 + ks
    int nb = bid >> 2, ks = bid & 3;
    int l = threadIdx.x;
    int col = nb * 16 + (l & 15);
    int kbase = ks * 32 + (l >> 4) * 8;
    unsigned short tmp[8];
#pragma unroll
    for (int m = 0; m < 8; ++m)
        tmp[m] = f2bf(gw1[(size_t)(kbase + m) * H + col]);
    *(uint4*)(gwp + ((size_t)bid * 64 + l) * 8) = *(uint4*)tmp;
}

// ---------------- CSR build: deg -> scan -> scatter ----------------
__global__ __launch_bounds__(256) void k_deg(const int* __restrict__ ei, int* __restrict__ deg)
{
    int e = blockIdx.x * 256 + threadIdx.x;
    if (e < N_EDGES) atomicAdd(&deg[ei[N_EDGES + e]], 1);
}

__global__ __launch_bounds__(256) void k_scan1(
    const int* __restrict__ deg, int* __restrict__ rowtmp, int* __restrict__ bsum)
{
    __shared__ int sh[256];
    int t = threadIdx.x;
    int i = blockIdx.x * 256 + t;
    int v = deg[i];
    sh[t] = v;
    __syncthreads();
    for (int off = 1; off < 256; off <<= 1) {
        int a = (t >= off) ? sh[t - off] : 0;
        __syncthreads();
        sh[t] += a;
        __syncthreads();
    }
    rowtmp[i] = sh[t] - v;                 // exclusive
    if (t == 255) bsum[blockIdx.x] = sh[255];
}

__global__ void k_scan2(int* __restrict__ bsum, int* __restrict__ boff)  // 1 block x 256
{
    __shared__ int sh[256];
    __shared__ int carry;
    int t = threadIdx.x;
    if (t == 0) carry = 0;
    __syncthreads();
    for (int base = 0; base < NB_SCAN; base += 256) {
        int i = base + t;
        int v = (i < NB_SCAN) ? bsum[i] : 0;
        sh[t] = v;
        __syncthreads();
        for (int off = 1; off < 256; off <<= 1) {
            int a = (t >= off) ? sh[t - off] : 0;
            __syncthreads();
            sh[t] += a;
            __syncthreads();
        }
        if (i < NB_SCAN) boff[i] = carry + sh[t] - v;
        __syncthreads();
        if (t == 0) carry += sh[255];
        __syncthreads();
    }
}

__global__ __launch_bounds__(256) void k_scan3(
    const int* __restrict__ rowtmp, const int* __restrict__ boff,
    int* __restrict__ rowptr, int* __restrict__ cursor)
{
    int i = blockIdx.x * 256 + threadIdx.x;
    int r = rowtmp[i] + boff[blockIdx.x];
    rowptr[i] = r;
    cursor[i] = r;
    if (i == 0) rowptr[N_NODES] = N_EDGES;
}

// scatter 32B records: {src, ea0..ea4, pad, pad}
__global__ __launch_bounds__(256) void k_scatter(
    const int* __restrict__ ei, const float* __restrict__ eattr,
    int* __restrict__ cursor, uint4* __restrict__ recs)
{
    int e = blockIdx.x * 256 + threadIdx.x;
    if (e >= N_EDGES) return;
    int d = ei[N_EDGES + e];
    const float* ar = eattr + (size_t)e * EF;
    float c0 = ar[0], c1 = ar[1], c2 = ar[2], c3 = ar[3], c4 = ar[4];
    int pos = atomicAdd(&cursor[d], 1);
    uint4 q0, q1;
    q0.x = (unsigned int)ei[e];
    q0.y = __builtin_bit_cast(unsigned int, c0);
    q0.z = __builtin_bit_cast(unsigned int, c1);
    q0.w = __builtin_bit_cast(unsigned int, c2);
    q1.x = __builtin_bit_cast(unsigned int, c3);
    q1.y = __builtin_bit_cast(unsigned int, c4);
    q1.z = 0; q1.w = 0;
    recs[2 * (size_t)pos]     = q0;
    recs[2 * (size_t)pos + 1] = q1;
}

// ---------------- K3: stream-fold aggregation; 8 nodes/wave, contiguous edge stream ----
// Wave walks [rowptr[n0], rowptr[n0+8]) in groups of 4 (always 4 gathers in flight,
// trip count = actual edges, not max-degree). Node boundaries flushed via wave-uniform
// while; per-node rowptr kept in lane registers, read via __shfl (no scratch array).
#define FOLD(jj, q0, q1, hv)                                                   \
    if ((jj) < jend) {                                                         \
        while ((jj) >= nend) {                                                 \
            *(unsigned int*)(aggb + (size_t)(n0 + cur) * H + 2 * l) =          \
                (unsigned int)f2bf(a0) | ((unsigned int)f2bf(a1) << 16);       \
            a0 = 0.f; a1 = 0.f; ++cur; nend = __shfl(rpv, cur + 1);            \
        }                                                                      \
        float ea0 = eb2.x, ea1 = eb2.y;                                        \
        float c0 = uif((q0).y), c1 = uif((q0).z), c2 = uif((q0).w);            \
        float c3 = uif((q1).x), c4 = uif((q1).y);                              \
        ea0 += c0 * ew2[0].x + c1 * ew2[1].x + c2 * ew2[2].x + c3 * ew2[3].x + c4 * ew2[4].x; \
        ea1 += c0 * ew2[0].y + c1 * ew2[1].y + c2 * ew2[2].y + c3 * ew2[3].y + c4 * ew2[4].y; \
        a0 += bf2f((hv) & 0xffffu) * ea0;                                      \
        a1 += bf2f((hv) >> 16) * ea1;                                          \
    }

__global__ __launch_bounds__(256) void k_agg(
    const int* __restrict__ rowptr, const uint4* __restrict__ recs,
    const float* __restrict__ edge_w, const float* __restrict__ edge_b,
    const unsigned short* __restrict__ hb, unsigned short* __restrict__ aggb)
{
    int w = threadIdx.x >> 6, l = threadIdx.x & 63;
    int n0 = (blockIdx.x * 4 + w) * 8;         // this wave: nodes n0..n0+7
    float2 ew2[EF];
#pragma unroll
    for (int k = 0; k < EF; ++k) ew2[k] = ((const float2*)(edge_w + k * H))[l];
    float2 eb2 = ((const float2*)edge_b)[l];

    int rpv = rowptr[n0 + (l < 9 ? l : 8)];    // lane i holds rowptr[n0+i], i=0..8
    int jbeg = __shfl(rpv, 0), jend = __shfl(rpv, 8);
    int cur = 0;
    int nend = __shfl(rpv, 1);
    float a0 = 0.f, a1 = 0.f;

    for (int j = jbeg; j < jend; j += 4) {
        int jc1 = min(j + 1, jend - 1);
        int jc2 = min(j + 2, jend - 1);
        int jc3 = min(j + 3, jend - 1);
        uint4 qa0 = recs[2 * (size_t)j],   qa1 = recs[2 * (size_t)j + 1];
        uint4 qb0 = recs[2 * (size_t)jc1], qb1 = recs[2 * (size_t)jc1 + 1];
        uint4 qc0 = recs[2 * (size_t)jc2], qc1 = recs[2 * (size_t)jc2 + 1];
        uint4 qd0 = recs[2 * (size_t)jc3], qd1 = recs[2 * (size_t)jc3 + 1];
        unsigned int hva = *(const unsigned int*)(hb + (size_t)(int)qa0.x * H + 2 * l);
        unsigned int hvb = *(const unsigned int*)(hb + (size_t)(int)qb0.x * H + 2 * l);
        unsigned int hvc = *(const unsigned int*)(hb + (size_t)(int)qc0.x * H + 2 * l);
        unsigned int hvd = *(const unsigned int*)(hb + (size_t)(int)qd0.x * H + 2 * l);
        FOLD(j,     qa0, qa1, hva);
        FOLD(j + 1, qb0, qb1, hvb);
        FOLD(j + 2, qc0, qc1, hvc);
        FOLD(j + 3, qd0, qd1, hvd);
    }
    // flush current node and any trailing zero-degree nodes
    while (cur < 8) {
        *(unsigned int*)(aggb + (size_t)(n0 + cur) * H + 2 * l) =
            (unsigned int)f2bf(a0) | ((unsigned int)f2bf(a1) << 16);
        a0 = 0.f; a1 = 0.f; ++cur;
    }
}

// ---------------- K4: MFMA dual-GEMM, A in swizzled LDS; BN partials -> pbuf ----------
__global__ __launch_bounds__(256) void k_gemm_mfma(
    const unsigned short* __restrict__ aggb,
    const unsigned short* __restrict__ hb,
    const unsigned short* __restrict__ wp,
    const float* __restrict__ relb,
    unsigned short* __restrict__ h2b,
    float* __restrict__ pbuf)                   // [256][NBLK] per-block partials
{
    __shared__ unsigned short smA[64 * 128];
    __shared__ unsigned short smH[64 * 128];
    int tid = threadIdx.x;
    int w = tid >> 6, l = tid & 63;
    int bid = blockIdx.x;
    int n0 = bid * 64;
    int lr = l & 15, hi = l >> 4;

    const char* aggp = (const char*)(aggb + (size_t)n0 * H);
    const char* hbp  = (const char*)(hb  + (size_t)n0 * H);
    char* sA = (char*)smA;
    char* sH = (char*)smH;
#pragma unroll
    for (int i = 0; i < 4; ++i) {
        int o = (i * 256 + tid) * 16;
        int row = o >> 8;
        int col = o & 255;
        int scol = col ^ ((row & 7) << 4);
        uint4 va = *(const uint4*)(aggp + o);
        uint4 vh = *(const uint4*)(hbp + o);
        *(uint4*)(sA + row * 256 + scol) = va;
        *(uint4*)(sH + row * 256 + scol) = vh;
    }
    __syncthreads();

    f32x4 acc[4][2];
#pragma unroll
    for (int rb = 0; rb < 4; ++rb) {
        acc[rb][0] = (f32x4){0.f, 0.f, 0.f, 0.f};
        acc[rb][1] = (f32x4){0.f, 0.f, 0.f, 0.f};
    }

    const bf16x8* wv = (const bf16x8*)wp;
#pragma unroll
    for (int ks = 0; ks < 4; ++ks) {            // agg half
        bf16x8 b0 = wv[((2 * w + 0) * 8 + ks) * 64 + l];
        bf16x8 b1 = wv[((2 * w + 1) * 8 + ks) * 64 + l];
#pragma unroll
        for (int rb = 0; rb < 4; ++rb) {
            int r = rb * 16 + lr;
            int bc = (ks * 64 + hi * 16) ^ ((r & 7) << 4);
            bf16x8 a = *(const bf16x8*)(sA + r * 256 + bc);
            acc[rb][0] = __builtin_amdgcn_mfma_f32_16x16x32_bf16(a, b0, acc[rb][0], 0, 0, 0);
            acc[rb][1] = __builtin_amdgcn_mfma_f32_16x16x32_bf16(a, b1, acc[rb][1], 0, 0, 0);
        }
    }
#pragma unroll
    for (int ks = 0; ks < 4; ++ks) {            // root half
        bf16x8 b0 = wv[((2 * w + 0) * 8 + 4 + ks) * 64 + l];
        bf16x8 b1 = wv[((2 * w + 1) * 8 + 4 + ks) * 64 + l];
#pragma unroll
        for (int rb = 0; rb < 4; ++rb) {
            int r = rb * 16 + lr;
            int bc = (ks * 64 + hi * 16) ^ ((r & 7) << 4);
            bf16x8 a = *(const bf16x8*)(sH + r * 256 + bc);
            acc[rb][0] = __builtin_amdgcn_mfma_f32_16x16x32_bf16(a, b0, acc[rb][0], 0, 0, 0);
            acc[rb][1] = __builtin_amdgcn_mfma_f32_16x16x32_bf16(a, b1, acc[rb][1], 0, 0, 0);
        }
    }

#pragma unroll
    for (int nbl = 0; nbl < 2; ++nbl) {
        int col = w * 32 + nbl * 16 + lr;
        float bs = relb[col];
        float csum = 0.f, csq = 0.f;
#pragma unroll
        for (int rb = 0; rb < 4; ++rb) {
#pragma unroll
            for (int jj = 0; jj < 4; ++jj) {
                float v = acc[rb][nbl][jj] + bs;
                h2b[(size_t)(n0 + rb * 16 + hi * 4 + jj) * H + col] = f2bf(v);
                csum += v; csq += v * v;
            }
        }
        csum += __shfl_xor(csum, 16); csum += __shfl_xor(csum, 32);
        csq  += __shfl_xor(csq, 16);  csq  += __shfl_xor(csq, 32);
        if (hi == 0) {
            pbuf[(size_t)col * NBLK + bid]         = csum;
            pbuf[(size_t)(128 + col) * NBLK + bid] = csq;
        }
    }
}

// ---------------- K5: reduce pbuf -> scale/shift ----------------
__global__ __launch_bounds__(256) void k_red(
    const float* __restrict__ pbuf, const float* __restrict__ gamma,
    const float* __restrict__ beta, float* __restrict__ stats)
{
    __shared__ float sh[8];
    int c = blockIdx.x;                 // 0..127
    int t = threadIdx.x;
    float s = 0.f, q = 0.f;
    const float* ps = pbuf + (size_t)c * NBLK;
    const float* pq = pbuf + (size_t)(128 + c) * NBLK;
    for (int i = t; i < NBLK; i += 256) { s += ps[i]; q += pq[i]; }
#pragma unroll
    for (int off = 32; off >= 1; off >>= 1) {
        s += __shfl_xor(s, off);
        q += __shfl_xor(q, off);
    }
    if ((t & 63) == 0) { sh[t >> 6] = s; sh[4 + (t >> 6)] = q; }
    __syncthreads();
    if (t == 0) {
        float S = sh[0] + sh[1] + sh[2] + sh[3];
        float Q = sh[4] + sh[5] + sh[6] + sh[7];
        float mean = S / (float)N_NODES;
        float var = fmaxf(Q / (float)N_NODES - mean * mean, 0.f);
        float scale = gamma[c] * rsqrtf(var + EPSV);
        stats[c] = scale;
        stats[128 + c] = beta[c] - mean * scale;
    }
}

// ---------------- K6: h = relu(h2*scale + shift + h_prev) ----------------
template<bool LAST>
__global__ __launch_bounds__(256) void k_bn_apply(
    const unsigned short* __restrict__ h2b, const float* __restrict__ stats,
    unsigned short* __restrict__ hb, float* __restrict__ h)
{
    __shared__ float ssc[H], ssh[H];
    int tid = threadIdx.x;
    if (tid < H) {
        ssc[tid] = stats[tid];
        ssh[tid] = stats[128 + tid];
    }
    __syncthreads();
    size_t base = ((size_t)blockIdx.x * 256 + tid) * 8;
    int c = (int)(base & 127);
    uint4 hv2 = *(const uint4*)(h2b + base);
    uint4 hvp = *(const uint4*)(hb + base);
    unsigned int u2[4] = {hv2.x, hv2.y, hv2.z, hv2.w};
    unsigned int up[4] = {hvp.x, hvp.y, hvp.z, hvp.w};
    float o[8];
#pragma unroll
    for (int k = 0; k < 4; ++k) {
        float vlo = bf2f(u2[k] & 0xffffu), vhi = bf2f(u2[k] >> 16);
        float plo = bf2f(up[k] & 0xffffu), phi = bf2f(up[k] >> 16);
        o[2 * k]     = fmaxf(vlo * ssc[c + 2 * k]     + ssh[c + 2 * k]     + plo, 0.f);
        o[2 * k + 1] = fmaxf(vhi * ssc[c + 2 * k + 1] + ssh[c + 2 * k + 1] + phi, 0.f);
    }
    uint4 pk;
    pk.x = (unsigned int)f2bf(o[0]) | ((unsigned int)f2bf(o[1]) << 16);
    pk.y = (unsigned int)f2bf(o[2]) | ((unsigned int)f2bf(o[3]) << 16);
    pk.z = (unsigned int)f2bf(o[4]) | ((unsigned int)f2bf(o[5]) << 16);
    pk.w = (unsigned int)f2bf(o[6]) | ((unsigned int)f2bf(o[7]) << 16);
    *(uint4*)(hb + base) = pk;
    if (LAST) {
        *(float4*)(h + base)     = make_float4(o[0], o[1], o[2], o[3]);
        *(float4*)(h + base + 4) = make_float4(o[4], o[5], o[6], o[7]);
    }
}

// ---------------- K7: fused gate MFMA + segment softmax + weighted pool (bf16 h) -------
// block = 1 graph = 64 nodes, 256 threads (4 waves)
__global__ __launch_bounds__(256) void k_gate_pool(
    const unsigned short* __restrict__ hb,
    const unsigned short* __restrict__ gwp,
    const float* __restrict__ b1, const float* __restrict__ w2,
    const float* __restrict__ b2, float* __restrict__ pooled)
{
    __shared__ float Red[512];
    __shared__ float al[64];
    int tid = threadIdx.x;
    int w = tid >> 6, l = tid & 63;
    int lr = l & 15, hi = l >> 4;
    int g = blockIdx.x;
    int n0 = g * SEG;

    f32x4 acc[4][2];
#pragma unroll
    for (int rb = 0; rb < 4; ++rb) {
        acc[rb][0] = (f32x4){0.f, 0.f, 0.f, 0.f};
        acc[rb][1] = (f32x4){0.f, 0.f, 0.f, 0.f};
    }
    const bf16x8* wv = (const bf16x8*)gwp;
#pragma unroll
    for (int ks = 0; ks < 4; ++ks) {
        bf16x8 bb0 = wv[((2 * w + 0) * 4 + ks) * 64 + l];
        bf16x8 bb1 = wv[((2 * w + 1) * 4 + ks) * 64 + l];
#pragma unroll
        for (int rb = 0; rb < 4; ++rb) {
            bf16x8 a = *(const bf16x8*)(hb + (size_t)(n0 + rb * 16 + lr) * H + ks * 32 + hi * 8);
            acc[rb][0] = __builtin_amdgcn_mfma_f32_16x16x32_bf16(a, bb0, acc[rb][0], 0, 0, 0);
            acc[rb][1] = __builtin_amdgcn_mfma_f32_16x16x32_bf16(a, bb1, acc[rb][1], 0, 0, 0);
        }
    }
    // gate row-partials: relu(v + b1) . w2 over this wave's 32 cols
    int col0 = w * 32 + lr, col1 = w * 32 + 16 + lr;
    float b10 = b1[col0], b11 = b1[col1];
    float w20 = w2[col0], w21 = w2[col1];
    float p[4][4];
#pragma unroll
    for (int rb = 0; rb < 4; ++rb)
#pragma unroll
        for (int jj = 0; jj < 4; ++jj) {
            float v0 = fmaxf(acc[rb][0][jj] + b10, 0.f);
            float v1 = fmaxf(acc[rb][1][jj] + b11, 0.f);
            float s = v0 * w20 + v1 * w21;
            s += __shfl_xor(s, 1); s += __shfl_xor(s, 2);
            s += __shfl_xor(s, 4); s += __shfl_xor(s, 8);
            p[rb][jj] = s;
        }
    if (lr == 0) {
#pragma unroll
        for (int rb = 0; rb < 4; ++rb)
#pragma unroll
            for (int jj = 0; jj < 4; ++jj)
                Red[w * 64 + rb * 16 + hi * 4 + jj] = p[rb][jj];
    }
    __syncthreads();
    if (tid < 64) {
        float gt = Red[tid] + Red[64 + tid] + Red[128 + tid] + Red[192 + tid] + b2[0];
        float m = gt;
#pragma unroll
        for (int off = 32; off >= 1; off >>= 1) m = fmaxf(m, __shfl_xor(m, off));
        float e = expf(gt - m);
        float s = e;
#pragma unroll
        for (int off = 32; off >= 1; off >>= 1) s += __shfl_xor(s, off);
        al[tid] = e / s;
    }
    __syncthreads();
    // weighted pool over bf16 hb: thread = (quarter qd of rows) x (2 channels)
    int cq = tid & 63, qd = tid >> 6;
    float p0 = 0.f, p1 = 0.f;
    const unsigned short* hbase = hb + (size_t)n0 * H;
    for (int j = qd * 16; j < qd * 16 + 16; ++j) {
        unsigned int hv = *(const unsigned int*)(hbase + (size_t)j * H + 2 * cq);
        float a = al[j];
        p0 += a * bf2f(hv & 0xffffu);
        p1 += a * bf2f(hv >> 16);
    }
    Red[qd * 128 + 2 * cq]     = p0;
    Red[qd * 128 + 2 * cq + 1] = p1;
    __syncthreads();
    if (tid < 128)
        pooled[(size_t)g * H + tid] = Red[tid] + Red[128 + tid] + Red[256 + tid] + Red[384 + tid];
}

// ---------------- K9: global_embedding = [pooled, gf] @ gi_w + gi_b ----------------
__global__ __launch_bounds__(128) void k_final(
    const float* __restrict__ pooled, const float* __restrict__ gfeat,
    const float* __restrict__ gf_w, const float* __restrict__ gf_b,
    const float* __restrict__ gi_w, const float* __restrict__ gi_b,
    float* __restrict__ out)
{
    int g = blockIdx.x, c = threadIdx.x;
    __shared__ float prow[H], gfs[H];
    prow[c] = pooled[(size_t)g * H + c];
    float gv = gf_b[c];
    const float* gr = gfeat + (size_t)g * GF;
#pragma unroll
    for (int k = 0; k < GF; ++k) gv += gr[k] * gf_w[k * H + c];
    gfs[c] = gv;
    __syncthreads();
    float acc = gi_b[c];
    for (int k = 0; k < H; ++k) acc += prow[k] * gi_w[k * H + c];
    for (int k = 0; k < H; ++k) acc += gfs[k] * gi_w[(H + k) * H + c];
    out[(size_t)N_NODES * H + (size_t)g * H + c] = acc;
}

extern "C" void kernel_launch(void* const* d_in, const int* in_sizes, int n_in,
                              void* d_out, int out_size, void* d_ws, size_t ws_size,
                              hipStream_t stream)
{
    const float* x       = (const float*)d_in[0];
    const int*   ei      = (const int*)d_in[1];
    const float* eattr   = (const float*)d_in[2];
    const float* gfeat   = (const float*)d_in[3];
    // d_in[4] = batch (unused; batch[n] == n/64)
    const float* node_w  = (const float*)d_in[5];
    const float* node_b  = (const float*)d_in[6];
    const float* edge_w  = (const float*)d_in[7];
    const float* edge_b  = (const float*)d_in[8];
    const float* rel_w   = (const float*)d_in[9];
    const float* rel_b   = (const float*)d_in[10];
    const float* root_w  = (const float*)d_in[11];
    const float* bn_g    = (const float*)d_in[12];
    const float* bn_b    = (const float*)d_in[13];
    const float* gate_w1 = (const float*)d_in[14];
    const float* gate_b1 = (const float*)d_in[15];
    const float* gate_w2 = (const float*)d_in[16];
    const float* gate_b2 = (const float*)d_in[17];
    const float* gf_w    = (const float*)d_in[18];
    const float* gf_b    = (const float*)d_in[19];
    const float* gi_w    = (const float*)d_in[20];
    const float* gi_b    = (const float*)d_in[21];

    float* h   = (float*)d_out;                          // [N,H] output 0 (written by last layer)
    float* out = (float*)d_out;

    char* wsb = (char*)d_ws;
    size_t off = 0;
    auto take = [&](size_t bytes) -> char* {
        char* r = wsb + off;
        off = (off + bytes + 63) & ~(size_t)63;
        return r;
    };
    unsigned short* h2b  = (unsigned short*)take((size_t)N_NODES * H * 2);
    unsigned short* hb   = (unsigned short*)take((size_t)N_NODES * H * 2);
    unsigned short* aggb = (unsigned short*)take((size_t)N_NODES * H * 2);
    unsigned short* wpck = (unsigned short*)take((size_t)LAYERS * 32768 * 2);
    unsigned short* gwp  = (unsigned short*)take((size_t)16384 * 2);
    float* pbuf   = (float*)take((size_t)256 * NBLK * 4);   // BN partials [256][NBLK]
    float* stats  = (float*)take((size_t)256 * 4);          // scale[128], shift[128]
    float* pooled = (float*)take((size_t)N_GRAPH * H * 4);
    int*   deg    = (int*)take((size_t)N_NODES * 4);
    int*   rowptr = (int*)take((size_t)(N_NODES + 1) * 4);
    int*   cursor = (int*)take((size_t)N_NODES * 4);
    int*   bsum   = (int*)take((size_t)NB_SCAN * 4);
    int*   boff   = (int*)take((size_t)NB_SCAN * 4);
    uint4* recs   = (uint4*)take((size_t)N_EDGES * 32);  // {src, ea0..4, pad2} per edge
    int*   rowtmp = cursor;   // alias ok (scan3 reads then writes same idx)

    // ---- CSR build + weight repack (once per launch) ----
    hipMemsetAsync(deg, 0, N_NODES * sizeof(int), stream);
    k_deg<<<(N_EDGES + 255) / 256, 256, 0, stream>>>(ei, deg);
    k_scan1<<<NB_SCAN, 256, 0, stream>>>(deg, rowtmp, bsum);
    k_scan2<<<1, 256, 0, stream>>>(bsum, boff);
    k_scan3<<<NB_SCAN, 256, 0, stream>>>(rowtmp, boff, rowptr, cursor);
    k_scatter<<<(N_EDGES + 255) / 256, 256, 0, stream>>>(ei, eattr, cursor, recs);
    k_wpack<<<LAYERS * 64, 64, 0, stream>>>(rel_w, root_w, wpck);
    k_wpack_gate<<<32, 64, 0, stream>>>(gate_w1, gwp);

    k_init_h<<<N_NODES * 16 / 256, 256, 0, stream>>>(x, node_w, node_b, hb);

    for (int i = 0; i < LAYERS; ++i) {
        k_agg<<<N_NODES / 32, 256, 0, stream>>>(rowptr, recs, edge_w, edge_b, hb, aggb);
        k_gemm_mfma<<<NBLK, 256, 0, stream>>>(
            aggb, hb, wpck + (size_t)i * 32768, rel_b + (size_t)i * H,
            h2b, pbuf);
        k_red<<<128, 256, 0, stream>>>(pbuf, bn_g + (size_t)i * H, bn_b + (size_t)i * H, stats);
        if (i < LAYERS - 1)
            k_bn_apply<false><<<N_NODES * H / 8 / 256, 256, 0, stream>>>(h2b, stats, hb, h);
        else
            k_bn_apply<true><<<N_NODES * H / 8 / 256, 256, 0, stream>>>(h2b, stats, hb, h);
    }

    k_gate_pool<<<N_GRAPH, 256, 0, stream>>>(hb, gwp, gate_b1, gate_w2, gate_b2, pooled);
    k_final<<<N_GRAPH, H, 0, stream>>>(pooled, gfeat, gf_w, gf_b, gi_w, gi_b, out);
}

// Round 13
// 932.511 us; speedup vs baseline: 1.1914x; 1.0459x over previous
//
#include <hip/hip_runtime.h>
#include <math.h>

#define N_NODES 204800
#define N_EDGES 600000
#define N_GRAPH 3200
#define H 128
#define NF 16
#define EF 5
#define GF 8
#define LAYERS 6
#define SEG 64
#define EPSV 1e-5f
#define NB_SCAN 800   // N_NODES / 256
#define NBLK 3200     // N_NODES / 64 (gemm blocks)

typedef __attribute__((ext_vector_type(8))) short bf16x8;
typedef __attribute__((ext_vector_type(4))) float f32x4;

__device__ inline float bf2f(unsigned int u) {            // low 16 bits = bf16
    return __builtin_bit_cast(float, u << 16);
}
__device__ inline unsigned short f2bf(float f) {          // RNE
    unsigned int u = __builtin_bit_cast(unsigned int, f);
    u += 0x7fffu + ((u >> 16) & 1u);
    return (unsigned short)(u >> 16);
}
__device__ inline float uif(unsigned int u) { return __builtin_bit_cast(float, u); }

// ---------------- node_w pack: B-frags, K padded 16->32 with zeros ----------------
// nwp[nb(8)][lane(64)][8]
__global__ __launch_bounds__(64) void k_wpack_init(
    const float* __restrict__ nw, unsigned short* __restrict__ nwp)
{
    int nb = blockIdx.x;           // 0..7
    int l = threadIdx.x;
    int col = nb * 16 + (l & 15);
    int kb = (l >> 4) * 8;
    unsigned short tmp[8];
#pragma unroll
    for (int m = 0; m < 8; ++m) {
        int k = kb + m;
        tmp[m] = (k < NF) ? f2bf(nw[(size_t)k * H + col]) : (unsigned short)0;
    }
    *(uint4*)(nwp + ((size_t)nb * 64 + l) * 8) = *(uint4*)tmp;
}

// ---------------- K1: hb = bf16(x @ node_w + node_b) via MFMA ----------------
// block = 256 (4 waves), 64 nodes; x tile staged bf16 in LDS (K padded to 32).
__global__ __launch_bounds__(256) void k_init_mfma(
    const float* __restrict__ x, const unsigned short* __restrict__ nwp,
    const float* __restrict__ node_b, unsigned short* __restrict__ hb)
{
    __shared__ unsigned short xt[64][40];       // padded stride: 2-way conflicts only
    int tid = threadIdx.x;
    int w = tid >> 6, l = tid & 63;
    int n0 = blockIdx.x * 64;
    int lr = l & 15, hi = l >> 4;

    // stage x: thread = (row, quarter); coalesced float4 read, bf16 LDS write
    int row = tid >> 2, q = tid & 3;
    float4 xv = *(const float4*)(x + (size_t)(n0 + row) * NF + q * 4);
    xt[row][q * 4 + 0] = f2bf(xv.x);
    xt[row][q * 4 + 1] = f2bf(xv.y);
    xt[row][q * 4 + 2] = f2bf(xv.z);
    xt[row][q * 4 + 3] = f2bf(xv.w);
    *(uint2*)&xt[row][16 + q * 4] = make_uint2(0, 0);   // zero pad k=16..31
    __syncthreads();

    f32x4 acc[4][2];
#pragma unroll
    for (int rb = 0; rb < 4; ++rb) {
        acc[rb][0] = (f32x4){0.f, 0.f, 0.f, 0.f};
        acc[rb][1] = (f32x4){0.f, 0.f, 0.f, 0.f};
    }
    const bf16x8* wv = (const bf16x8*)nwp;
    bf16x8 b0 = wv[(2 * w + 0) * 64 + l];
    bf16x8 b1 = wv[(2 * w + 1) * 64 + l];
#pragma unroll
    for (int rb = 0; rb < 4; ++rb) {
        bf16x8 a = *(const bf16x8*)&xt[rb * 16 + lr][hi * 8];
        acc[rb][0] = __builtin_amdgcn_mfma_f32_16x16x32_bf16(a, b0, acc[rb][0], 0, 0, 0);
        acc[rb][1] = __builtin_amdgcn_mfma_f32_16x16x32_bf16(a, b1, acc[rb][1], 0, 0, 0);
    }

#pragma unroll
    for (int nbl = 0; nbl < 2; ++nbl) {
        int col = w * 32 + nbl * 16 + lr;
        float bs = node_b[col];
#pragma unroll
        for (int rb = 0; rb < 4; ++rb)
#pragma unroll
            for (int jj = 0; jj < 4; ++jj)
                hb[(size_t)(n0 + rb * 16 + hi * 4 + jj) * H + col] = f2bf(acc[rb][nbl][jj] + bs);
    }
}

// ---------------- W repack: [rel|root] -> MFMA B-fragment order, bf16 ----------------
__global__ __launch_bounds__(64) void k_wpack(
    const float* __restrict__ relw, const float* __restrict__ rootw,
    unsigned short* __restrict__ wp)
{
    int bid = blockIdx.x;          // i*64 + nb*8 + ks
    int i = bid >> 6, f = bid & 63;
    int nb = f >> 3, ks = f & 7;
    int l = threadIdx.x;
    const float* src = (ks < 4) ? (relw + (size_t)i * H * H) : (rootw + (size_t)i * H * H);
    int ksl = ks & 3;
    int col = nb * 16 + (l & 15);
    int kbase = ksl * 32 + (l >> 4) * 8;
    unsigned short tmp[8];
#pragma unroll
    for (int m = 0; m < 8; ++m)
        tmp[m] = f2bf(src[(size_t)(kbase + m) * H + col]);
    *(uint4*)(wp + ((size_t)bid * 64 + l) * 8) = *(uint4*)tmp;
}

// gate_w1 pack: gwp[nb(8)][ks(4)][lane(64)][8]
__global__ __launch_bounds__(64) void k_wpack_gate(
    const float* __restrict__ gw1, unsigned short* __restrict__ gwp)
{
    int bid = blockIdx.x;          // nb*4 + ks
    int nb = bid >> 2, ks = bid & 3;
    int l = threadIdx.x;
    int col = nb * 16 + (l & 15);
    int kbase = ks * 32 + (l >> 4) * 8;
    unsigned short tmp[8];
#pragma unroll
    for (int m = 0; m < 8; ++m)
        tmp[m] = f2bf(gw1[(size_t)(kbase + m) * H + col]);
    *(uint4*)(gwp + ((size_t)bid * 64 + l) * 8) = *(uint4*)tmp;
}

// ---------------- CSR build: deg -> scan -> scatter ----------------
__global__ __launch_bounds__(256) void k_deg(const int* __restrict__ ei, int* __restrict__ deg)
{
    int e = blockIdx.x * 256 + threadIdx.x;
    if (e < N_EDGES) atomicAdd(&deg[ei[N_EDGES + e]], 1);
}

__global__ __launch_bounds__(256) void k_scan1(
    const int* __restrict__ deg, int* __restrict__ rowtmp, int* __restrict__ bsum)
{
    __shared__ int sh[256];
    int t = threadIdx.x;
    int i = blockIdx.x * 256 + t;
    int v = deg[i];
    sh[t] = v;
    __syncthreads();
    for (int off = 1; off < 256; off <<= 1) {
        int a = (t >= off) ? sh[t - off] : 0;
        __syncthreads();
        sh[t] += a;
        __syncthreads();
    }
    rowtmp[i] = sh[t] - v;                 // exclusive
    if (t == 255) bsum[blockIdx.x] = sh[255];
}

__global__ void k_scan2(int* __restrict__ bsum, int* __restrict__ boff)  // 1 block x 256
{
    __shared__ int sh[256];
    __shared__ int carry;
    int t = threadIdx.x;
    if (t == 0) carry = 0;
    __syncthreads();
    for (int base = 0; base < NB_SCAN; base += 256) {
        int i = base + t;
        int v = (i < NB_SCAN) ? bsum[i] : 0;
        sh[t] = v;
        __syncthreads();
        for (int off = 1; off < 256; off <<= 1) {
            int a = (t >= off) ? sh[t - off] : 0;
            __syncthreads();
            sh[t] += a;
            __syncthreads();
        }
        if (i < NB_SCAN) boff[i] = carry + sh[t] - v;
        __syncthreads();
        if (t == 0) carry += sh[255];
        __syncthreads();
    }
}

__global__ __launch_bounds__(256) void k_scan3(
    const int* __restrict__ rowtmp, const int* __restrict__ boff,
    int* __restrict__ rowptr, int* __restrict__ cursor)
{
    int i = blockIdx.x * 256 + threadIdx.x;
    int r = rowtmp[i] + boff[blockIdx.x];
    rowptr[i] = r;
    cursor[i] = r;
    if (i == 0) rowptr[N_NODES] = N_EDGES;
}

// scatter 32B records: {src, ea0..ea4, pad, pad}
__global__ __launch_bounds__(256) void k_scatter(
    const int* __restrict__ ei, const float* __restrict__ eattr,
    int* __restrict__ cursor, uint4* __restrict__ recs)
{
    int e = blockIdx.x * 256 + threadIdx.x;
    if (e >= N_EDGES) return;
    int d = ei[N_EDGES + e];
    const float* ar = eattr + (size_t)e * EF;
    float c0 = ar[0], c1 = ar[1], c2 = ar[2], c3 = ar[3], c4 = ar[4];
    int pos = atomicAdd(&cursor[d], 1);
    uint4 q0, q1;
    q0.x = (unsigned int)ei[e];
    q0.y = __builtin_bit_cast(unsigned int, c0);
    q0.z = __builtin_bit_cast(unsigned int, c1);
    q0.w = __builtin_bit_cast(unsigned int, c2);
    q1.x = __builtin_bit_cast(unsigned int, c3);
    q1.y = __builtin_bit_cast(unsigned int, c4);
    q1.z = 0; q1.w = 0;
    recs[2 * (size_t)pos]     = q0;
    recs[2 * (size_t)pos + 1] = q1;
}

// ---------------- K3: stream-fold aggregation; 8 nodes/wave, contiguous edge stream ----
#define FOLD(jj, q0, q1, hv)                                                   \
    if ((jj) < jend) {                                                         \
        while ((jj) >= nend) {                                                 \
            *(unsigned int*)(aggb + (size_t)(n0 + cur) * H + 2 * l) =          \
                (unsigned int)f2bf(a0) | ((unsigned int)f2bf(a1) << 16);       \
            a0 = 0.f; a1 = 0.f; ++cur; nend = __shfl(rpv, cur + 1);            \
        }                                                                      \
        float ea0 = eb2.x, ea1 = eb2.y;                                        \
        float c0 = uif((q0).y), c1 = uif((q0).z), c2 = uif((q0).w);            \
        float c3 = uif((q1).x), c4 = uif((q1).y);                              \
        ea0 += c0 * ew2[0].x + c1 * ew2[1].x + c2 * ew2[2].x + c3 * ew2[3].x + c4 * ew2[4].x; \
        ea1 += c0 * ew2[0].y + c1 * ew2[1].y + c2 * ew2[2].y + c3 * ew2[3].y + c4 * ew2[4].y; \
        a0 += bf2f((hv) & 0xffffu) * ea0;                                      \
        a1 += bf2f((hv) >> 16) * ea1;                                          \
    }

__global__ __launch_bounds__(256) void k_agg(
    const int* __restrict__ rowptr, const uint4* __restrict__ recs,
    const float* __restrict__ edge_w, const float* __restrict__ edge_b,
    const unsigned short* __restrict__ hb, unsigned short* __restrict__ aggb)
{
    int w = threadIdx.x >> 6, l = threadIdx.x & 63;
    int n0 = (blockIdx.x * 4 + w) * 8;         // this wave: nodes n0..n0+7
    float2 ew2[EF];
#pragma unroll
    for (int k = 0; k < EF; ++k) ew2[k] = ((const float2*)(edge_w + k * H))[l];
    float2 eb2 = ((const float2*)edge_b)[l];

    int rpv = rowptr[n0 + (l < 9 ? l : 8)];    // lane i holds rowptr[n0+i], i=0..8
    int jbeg = __shfl(rpv, 0), jend = __shfl(rpv, 8);
    int cur = 0;
    int nend = __shfl(rpv, 1);
    float a0 = 0.f, a1 = 0.f;

    for (int j = jbeg; j < jend; j += 4) {
        int jc1 = min(j + 1, jend - 1);
        int jc2 = min(j + 2, jend - 1);
        int jc3 = min(j + 3, jend - 1);
        uint4 qa0 = recs[2 * (size_t)j],   qa1 = recs[2 * (size_t)j + 1];
        uint4 qb0 = recs[2 * (size_t)jc1], qb1 = recs[2 * (size_t)jc1 + 1];
        uint4 qc0 = recs[2 * (size_t)jc2], qc1 = recs[2 * (size_t)jc2 + 1];
        uint4 qd0 = recs[2 * (size_t)jc3], qd1 = recs[2 * (size_t)jc3 + 1];
        unsigned int hva = *(const unsigned int*)(hb + (size_t)(int)qa0.x * H + 2 * l);
        unsigned int hvb = *(const unsigned int*)(hb + (size_t)(int)qb0.x * H + 2 * l);
        unsigned int hvc = *(const unsigned int*)(hb + (size_t)(int)qc0.x * H + 2 * l);
        unsigned int hvd = *(const unsigned int*)(hb + (size_t)(int)qd0.x * H + 2 * l);
        FOLD(j,     qa0, qa1, hva);
        FOLD(j + 1, qb0, qb1, hvb);
        FOLD(j + 2, qc0, qc1, hvc);
        FOLD(j + 3, qd0, qd1, hvd);
    }
    while (cur < 8) {
        *(unsigned int*)(aggb + (size_t)(n0 + cur) * H + 2 * l) =
            (unsigned int)f2bf(a0) | ((unsigned int)f2bf(a1) << 16);
        a0 = 0.f; a1 = 0.f; ++cur;
    }
}

// ---------------- K4: MFMA dual-GEMM, A in swizzled LDS; BN partials -> pbuf ----------
__global__ __launch_bounds__(256) void k_gemm_mfma(
    const unsigned short* __restrict__ aggb,
    const unsigned short* __restrict__ hb,
    const unsigned short* __restrict__ wp,
    const float* __restrict__ relb,
    unsigned short* __restrict__ h2b,
    float* __restrict__ pbuf)                   // [256][NBLK] per-block partials
{
    __shared__ unsigned short smA[64 * 128];
    __shared__ unsigned short smH[64 * 128];
    int tid = threadIdx.x;
    int w = tid >> 6, l = tid & 63;
    int bid = blockIdx.x;
    int n0 = bid * 64;
    int lr = l & 15, hi = l >> 4;

    const char* aggp = (const char*)(aggb + (size_t)n0 * H);
    const char* hbp  = (const char*)(hb  + (size_t)n0 * H);
    char* sA = (char*)smA;
    char* sH = (char*)smH;
#pragma unroll
    for (int i = 0; i < 4; ++i) {
        int o = (i * 256 + tid) * 16;
        int row = o >> 8;
        int col = o & 255;
        int scol = col ^ ((row & 7) << 4);
        uint4 va = *(const uint4*)(aggp + o);
        uint4 vh = *(const uint4*)(hbp + o);
        *(uint4*)(sA + row * 256 + scol) = va;
        *(uint4*)(sH + row * 256 + scol) = vh;
    }
    __syncthreads();

    f32x4 acc[4][2];
#pragma unroll
    for (int rb = 0; rb < 4; ++rb) {
        acc[rb][0] = (f32x4){0.f, 0.f, 0.f, 0.f};
        acc[rb][1] = (f32x4){0.f, 0.f, 0.f, 0.f};
    }

    const bf16x8* wv = (const bf16x8*)wp;
#pragma unroll
    for (int ks = 0; ks < 4; ++ks) {            // agg half
        bf16x8 b0 = wv[((2 * w + 0) * 8 + ks) * 64 + l];
        bf16x8 b1 = wv[((2 * w + 1) * 8 + ks) * 64 + l];
#pragma unroll
        for (int rb = 0; rb < 4; ++rb) {
            int r = rb * 16 + lr;
            int bc = (ks * 64 + hi * 16) ^ ((r & 7) << 4);
            bf16x8 a = *(const bf16x8*)(sA + r * 256 + bc);
            acc[rb][0] = __builtin_amdgcn_mfma_f32_16x16x32_bf16(a, b0, acc[rb][0], 0, 0, 0);
            acc[rb][1] = __builtin_amdgcn_mfma_f32_16x16x32_bf16(a, b1, acc[rb][1], 0, 0, 0);
        }
    }
#pragma unroll
    for (int ks = 0; ks < 4; ++ks) {            // root half
        bf16x8 b0 = wv[((2 * w + 0) * 8 + 4 + ks) * 64 + l];
        bf16x8 b1 = wv[((2 * w + 1) * 8 + 4 + ks) * 64 + l];
#pragma unroll
        for (int rb = 0; rb < 4; ++rb) {
            int r = rb * 16 + lr;
            int bc = (ks * 64 + hi * 16) ^ ((r & 7) << 4);
            bf16x8 a = *(const bf16x8*)(sH + r * 256 + bc);
            acc[rb][0] = __builtin_amdgcn_mfma_f32_16x16x32_bf16(a, b0, acc[rb][0], 0, 0, 0);
            acc[rb][1] = __builtin_amdgcn_mfma_f32_16x16x32_bf16(a, b1, acc[rb][1], 0, 0, 0);
        }
    }

#pragma unroll
    for (int nbl = 0; nbl < 2; ++nbl) {
        int col = w * 32 + nbl * 16 + lr;
        float bs = relb[col];
        float csum = 0.f, csq = 0.f;
#pragma unroll
        for (int rb = 0; rb < 4; ++rb) {
#pragma unroll
            for (int jj = 0; jj < 4; ++jj) {
                float v = acc[rb][nbl][jj] + bs;
                h2b[(size_t)(n0 + rb * 16 + hi * 4 + jj) * H + col] = f2bf(v);
                csum += v; csq += v * v;
            }
        }
        csum += __shfl_xor(csum, 16); csum += __shfl_xor(csum, 32);
        csq  += __shfl_xor(csq, 16);  csq  += __shfl_xor(csq, 32);
        if (hi == 0) {
            pbuf[(size_t)col * NBLK + bid]         = csum;
            pbuf[(size_t)(128 + col) * NBLK + bid] = csq;
        }
    }
}

// ---------------- K5: reduce pbuf -> scale/shift ----------------
__global__ __launch_bounds__(256) void k_red(
    const float* __restrict__ pbuf, const float* __restrict__ gamma,
    const float* __restrict__ beta, float* __restrict__ stats)
{
    __shared__ float sh[8];
    int c = blockIdx.x;                 // 0..127
    int t = threadIdx.x;
    float s = 0.f, q = 0.f;
    const float* ps = pbuf + (size_t)c * NBLK;
    const float* pq = pbuf + (size_t)(128 + c) * NBLK;
    for (int i = t; i < NBLK; i += 256) { s += ps[i]; q += pq[i]; }
#pragma unroll
    for (int off = 32; off >= 1; off >>= 1) {
        s += __shfl_xor(s, off);
        q += __shfl_xor(q, off);
    }
    if ((t & 63) == 0) { sh[t >> 6] = s; sh[4 + (t >> 6)] = q; }
    __syncthreads();
    if (t == 0) {
        float S = sh[0] + sh[1] + sh[2] + sh[3];
        float Q = sh[4] + sh[5] + sh[6] + sh[7];
        float mean = S / (float)N_NODES;
        float var = fmaxf(Q / (float)N_NODES - mean * mean, 0.f);
        float scale = gamma[c] * rsqrtf(var + EPSV);
        stats[c] = scale;
        stats[128 + c] = beta[c] - mean * scale;
    }
}

// ---------------- K6: h = relu(h2*scale + shift + h_prev) ----------------
template<bool LAST>
__global__ __launch_bounds__(256) void k_bn_apply(
    const unsigned short* __restrict__ h2b, const float* __restrict__ stats,
    unsigned short* __restrict__ hb, float* __restrict__ h)
{
    __shared__ float ssc[H], ssh[H];
    int tid = threadIdx.x;
    if (tid < H) {
        ssc[tid] = stats[tid];
        ssh[tid] = stats[128 + tid];
    }
    __syncthreads();
    size_t base = ((size_t)blockIdx.x * 256 + tid) * 8;
    int c = (int)(base & 127);
    uint4 hv2 = *(const uint4*)(h2b + base);
    uint4 hvp = *(const uint4*)(hb + base);
    unsigned int u2[4] = {hv2.x, hv2.y, hv2.z, hv2.w};
    unsigned int up[4] = {hvp.x, hvp.y, hvp.z, hvp.w};
    float o[8];
#pragma unroll
    for (int k = 0; k < 4; ++k) {
        float vlo = bf2f(u2[k] & 0xffffu), vhi = bf2f(u2[k] >> 16);
        float plo = bf2f(up[k] & 0xffffu), phi = bf2f(up[k] >> 16);
        o[2 * k]     = fmaxf(vlo * ssc[c + 2 * k]     + ssh[c + 2 * k]     + plo, 0.f);
        o[2 * k + 1] = fmaxf(vhi * ssc[c + 2 * k + 1] + ssh[c + 2 * k + 1] + phi, 0.f);
    }
    uint4 pk;
    pk.x = (unsigned int)f2bf(o[0]) | ((unsigned int)f2bf(o[1]) << 16);
    pk.y = (unsigned int)f2bf(o[2]) | ((unsigned int)f2bf(o[3]) << 16);
    pk.z = (unsigned int)f2bf(o[4]) | ((unsigned int)f2bf(o[5]) << 16);
    pk.w = (unsigned int)f2bf(o[6]) | ((unsigned int)f2bf(o[7]) << 16);
    *(uint4*)(hb + base) = pk;
    if (LAST) {
        *(float4*)(h + base)     = make_float4(o[0], o[1], o[2], o[3]);
        *(float4*)(h + base + 4) = make_float4(o[4], o[5], o[6], o[7]);
    }
}

// ---------------- K7: fused gate MFMA + segment softmax + weighted pool (bf16 h) -------
__global__ __launch_bounds__(256) void k_gate_pool(
    const unsigned short* __restrict__ hb,
    const unsigned short* __restrict__ gwp,
    const float* __restrict__ b1, const float* __restrict__ w2,
    const float* __restrict__ b2, float* __restrict__ pooled)
{
    __shared__ float Red[512];
    __shared__ float al[64];
    int tid = threadIdx.x;
    int w = tid >> 6, l = tid & 63;
    int lr = l & 15, hi = l >> 4;
    int g = blockIdx.x;
    int n0 = g * SEG;

    f32x4 acc[4][2];
#pragma unroll
    for (int rb = 0; rb < 4; ++rb) {
        acc[rb][0] = (f32x4){0.f, 0.f, 0.f, 0.f};
        acc[rb][1] = (f32x4){0.f, 0.f, 0.f, 0.f};
    }
    const bf16x8* wv = (const bf16x8*)gwp;
#pragma unroll
    for (int ks = 0; ks < 4; ++ks) {
        bf16x8 bb0 = wv[((2 * w + 0) * 4 + ks) * 64 + l];
        bf16x8 bb1 = wv[((2 * w + 1) * 4 + ks) * 64 + l];
#pragma unroll
        for (int rb = 0; rb < 4; ++rb) {
            bf16x8 a = *(const bf16x8*)(hb + (size_t)(n0 + rb * 16 + lr) * H + ks * 32 + hi * 8);
            acc[rb][0] = __builtin_amdgcn_mfma_f32_16x16x32_bf16(a, bb0, acc[rb][0], 0, 0, 0);
            acc[rb][1] = __builtin_amdgcn_mfma_f32_16x16x32_bf16(a, bb1, acc[rb][1], 0, 0, 0);
        }
    }
    int col0 = w * 32 + lr, col1 = w * 32 + 16 + lr;
    float b10 = b1[col0], b11 = b1[col1];
    float w20 = w2[col0], w21 = w2[col1];
    float p[4][4];
#pragma unroll
    for (int rb = 0; rb < 4; ++rb)
#pragma unroll
        for (int jj = 0; jj < 4; ++jj) {
            float v0 = fmaxf(acc[rb][0][jj] + b10, 0.f);
            float v1 = fmaxf(acc[rb][1][jj] + b11, 0.f);
            float s = v0 * w20 + v1 * w21;
            s += __shfl_xor(s, 1); s += __shfl_xor(s, 2);
            s += __shfl_xor(s, 4); s += __shfl_xor(s, 8);
            p[rb][jj] = s;
        }
    if (lr == 0) {
#pragma unroll
        for (int rb = 0; rb < 4; ++rb)
#pragma unroll
            for (int jj = 0; jj < 4; ++jj)
                Red[w * 64 + rb * 16 + hi * 4 + jj] = p[rb][jj];
    }
    __syncthreads();
    if (tid < 64) {
        float gt = Red[tid] + Red[64 + tid] + Red[128 + tid] + Red[192 + tid] + b2[0];
        float m = gt;
#pragma unroll
        for (int off = 32; off >= 1; off >>= 1) m = fmaxf(m, __shfl_xor(m, off));
        float e = expf(gt - m);
        float s = e;
#pragma unroll
        for (int off = 32; off >= 1; off >>= 1) s += __shfl_xor(s, off);
        al[tid] = e / s;
    }
    __syncthreads();
    int cq = tid & 63, qd = tid >> 6;
    float p0 = 0.f, p1 = 0.f;
    const unsigned short* hbase = hb + (size_t)n0 * H;
    for (int j = qd * 16; j < qd * 16 + 16; ++j) {
        unsigned int hv = *(const unsigned int*)(hbase + (size_t)j * H + 2 * cq);
        float a = al[j];
        p0 += a * bf2f(hv & 0xffffu);
        p1 += a * bf2f(hv >> 16);
    }
    Red[qd * 128 + 2 * cq]     = p0;
    Red[qd * 128 + 2 * cq + 1] = p1;
    __syncthreads();
    if (tid < 128)
        pooled[(size_t)g * H + tid] = Red[tid] + Red[128 + tid] + Red[256 + tid] + Red[384 + tid];
}

// ---------------- K9: global_embedding = [pooled, gf] @ gi_w + gi_b ----------------
__global__ __launch_bounds__(128) void k_final(
    const float* __restrict__ pooled, const float* __restrict__ gfeat,
    const float* __restrict__ gf_w, const float* __restrict__ gf_b,
    const float* __restrict__ gi_w, const float* __restrict__ gi_b,
    float* __restrict__ out)
{
    int g = blockIdx.x, c = threadIdx.x;
    __shared__ float prow[H], gfs[H];
    prow[c] = pooled[(size_t)g * H + c];
    float gv = gf_b[c];
    const float* gr = gfeat + (size_t)g * GF;
#pragma unroll
    for (int k = 0; k < GF; ++k) gv += gr[k] * gf_w[k * H + c];
    gfs[c] = gv;
    __syncthreads();
    float acc = gi_b[c];
    for (int k = 0; k < H; ++k) acc += prow[k] * gi_w[k * H + c];
    for (int k = 0; k < H; ++k) acc += gfs[k] * gi_w[(H + k) * H + c];
    out[(size_t)N_NODES * H + (size_t)g * H + c] = acc;
}

extern "C" void kernel_launch(void* const* d_in, const int* in_sizes, int n_in,
                              void* d_out, int out_size, void* d_ws, size_t ws_size,
                              hipStream_t stream)
{
    const float* x       = (const float*)d_in[0];
    const int*   ei      = (const int*)d_in[1];
    const float* eattr   = (const float*)d_in[2];
    const float* gfeat   = (const float*)d_in[3];
    // d_in[4] = batch (unused; batch[n] == n/64)
    const float* node_w  = (const float*)d_in[5];
    const float* node_b  = (const float*)d_in[6];
    const float* edge_w  = (const float*)d_in[7];
    const float* edge_b  = (const float*)d_in[8];
    const float* rel_w   = (const float*)d_in[9];
    const float* rel_b   = (const float*)d_in[10];
    const float* root_w  = (const float*)d_in[11];
    const float* bn_g    = (const float*)d_in[12];
    const float* bn_b    = (const float*)d_in[13];
    const float* gate_w1 = (const float*)d_in[14];
    const float* gate_b1 = (const float*)d_in[15];
    const float* gate_w2 = (const float*)d_in[16];
    const float* gate_b2 = (const float*)d_in[17];
    const float* gf_w    = (const float*)d_in[18];
    const float* gf_b    = (const float*)d_in[19];
    const float* gi_w    = (const float*)d_in[20];
    const float* gi_b    = (const float*)d_in[21];

    float* h   = (float*)d_out;                          // [N,H] output 0 (written by last layer)
    float* out = (float*)d_out;

    char* wsb = (char*)d_ws;
    size_t off = 0;
    auto take = [&](size_t bytes) -> char* {
        char* r = wsb + off;
        off = (off + bytes + 63) & ~(size_t)63;
        return r;
    };
    unsigned short* h2b  = (unsigned short*)take((size_t)N_NODES * H * 2);
    unsigned short* hb   = (unsigned short*)take((size_t)N_NODES * H * 2);
    unsigned short* aggb = (unsigned short*)take((size_t)N_NODES * H * 2);
    unsigned short* wpck = (unsigned short*)take((size_t)LAYERS * 32768 * 2);
    unsigned short* gwp  = (unsigned short*)take((size_t)16384 * 2);
    unsigned short* nwp  = (unsigned short*)take((size_t)4096 * 2);   // init W pack
    float* pbuf   = (float*)take((size_t)256 * NBLK * 4);   // BN partials [256][NBLK]
    float* stats  = (float*)take((size_t)256 * 4);          // scale[128], shift[128]
    float* pooled = (float*)take((size_t)N_GRAPH * H * 4);
    int*   deg    = (int*)take((size_t)N_NODES * 4);
    int*   rowptr = (int*)take((size_t)(N_NODES + 1) * 4);
    int*   cursor = (int*)take((size_t)N_NODES * 4);
    int*   bsum   = (int*)take((size_t)NB_SCAN * 4);
    int*   boff   = (int*)take((size_t)NB_SCAN * 4);
    uint4* recs   = (uint4*)take((size_t)N_EDGES * 32);  // {src, ea0..4, pad2} per edge
    int*   rowtmp = cursor;   // alias ok (scan3 reads then writes same idx)

    // ---- CSR build + weight repack (once per launch) ----
    hipMemsetAsync(deg, 0, N_NODES * sizeof(int), stream);
    k_deg<<<(N_EDGES + 255) / 256, 256, 0, stream>>>(ei, deg);
    k_scan1<<<NB_SCAN, 256, 0, stream>>>(deg, rowtmp, bsum);
    k_scan2<<<1, 256, 0, stream>>>(bsum, boff);
    k_scan3<<<NB_SCAN, 256, 0, stream>>>(rowtmp, boff, rowptr, cursor);
    k_scatter<<<(N_EDGES + 255) / 256, 256, 0, stream>>>(ei, eattr, cursor, recs);
    k_wpack<<<LAYERS * 64, 64, 0, stream>>>(rel_w, root_w, wpck);
    k_wpack_gate<<<32, 64, 0, stream>>>(gate_w1, gwp);
    k_wpack_init<<<8, 64, 0, stream>>>(node_w, nwp);

    k_init_mfma<<<NBLK, 256, 0, stream>>>(x, nwp, node_b, hb);

    for (int i = 0; i < LAYERS; ++i) {
        k_agg<<<N_NODES / 32, 256, 0, stream>>>(rowptr, recs, edge_w, edge_b, hb, aggb);
        k_gemm_mfma<<<NBLK, 256, 0, stream>>>(
            aggb, hb, wpck + (size_t)i * 32768, rel_b + (size_t)i * H,
            h2b, pbuf);
        k_red<<<128, 256, 0, stream>>>(pbuf, bn_g + (size_t)i * H, bn_b + (size_t)i * H, stats);
        if (i < LAYERS - 1)
            k_bn_apply<false><<<N_NODES * H / 8 / 256, 256, 0, stream>>>(h2b, stats, hb, h);
        else
            k_bn_apply<true><<<N_NODES * H / 8 / 256, 256, 0, stream>>>(h2b, stats, hb, h);
    }

    k_gate_pool<<<N_GRAPH, 256, 0, stream>>>(hb, gwp, gate_b1, gate_w2, gate_b2, pooled);
    k_final<<<N_GRAPH, H, 0, stream>>>(pooled, gfeat, gf_w, gf_b, gi_w, gi_b, out);
}